// Round 8
// baseline (3272.329 us; speedup 1.0000x reference)
//
#include <hip/hip_runtime.h>

// Persistent LSTM decoder, fence-lite cross-WG pipeline, fp16 datapath.
// 64 gate WGs (16 units x 4 gates) + 16 logit WGs (64 vocab rows), 512 thr / 8 waves
// (wave = rt-pair x b-half x k-half -> 2 waves/SIMD latency hiding).
// h exchanged as a single fp16 plane via sc1 write-through stores (vmcnt(0)-acked
// before flag); consumers use PLAIN cached loads on a RING-deep slot ring with a
// wave0-only agent acquire fence every FCAD steps (FCAD <= RING - GUARD + 1).
// Logit output: finalize into gl in-place, then transposed cooperative
// nontemporal stores -> full 64B lines (kills the 4x write-amp + RMW fetch).

#define TT 256
#define NH 1024
#define NV 1000
#define WROW 2024   // V + H
#define NGATE 64
#define NLOGIT 16

typedef __attribute__((ext_vector_type(8))) short short8;
typedef __attribute__((ext_vector_type(8))) _Float16 half8;
typedef __attribute__((ext_vector_type(4))) float f32x4;

#define AGT __HIP_MEMORY_SCOPE_AGENT

__device__ __forceinline__ unsigned short f2bf(float f) {
    unsigned int u = __float_as_uint(f);
    u += 0x7fffu + ((u >> 16) & 1u);
    return (unsigned short)(u >> 16);
}
__device__ __forceinline__ float bf2f(unsigned short s) {
    return __uint_as_float(((unsigned int)s) << 16);
}
__device__ __forceinline__ unsigned short f2h(float f) {
    return __builtin_bit_cast(unsigned short, (_Float16)f);
}
__device__ __forceinline__ half8 as_h8(short8 s) {
    return __builtin_bit_cast(half8, s);
}
__device__ __forceinline__ float sigm(float x) {
    return __builtin_amdgcn_rcpf(1.0f + __expf(-x));
}
__device__ __forceinline__ float tanh_f(float x) {
    return 2.0f * __builtin_amdgcn_rcpf(1.0f + __expf(-2.0f * x)) - 1.0f;
}

// ---- one-time: transpose-cast embedding block Ww[:, :V] -> embT[V][4096] bf16
__global__ void embT_kernel(const float* __restrict__ Ww, unsigned short* __restrict__ embT) {
    __shared__ unsigned short tile[64][80];
    const int rt = blockIdx.x & 63, vt = blockIdx.x >> 6;
    const int r0 = rt * 64, v0 = vt * 64;
    const int t = threadIdx.x;
    {
        int rr = t >> 2, c0 = (t & 3) * 16;
        for (int j = 0; j < 16; ++j) {
            int v = v0 + c0 + j;
            float x = (v < NV) ? Ww[(size_t)(r0 + rr) * WROW + v] : 0.f;
            tile[c0 + j][rr] = f2bf(x);
        }
    }
    __syncthreads();
    {
        int vv = t >> 2, k0 = (t & 3) * 16;
        int v = v0 + vv;
        if (v < NV)
            for (int j = 0; j < 16; ++j)
                embT[(size_t)v * 4096 + r0 + k0 + j] = tile[vv][k0 + j];
    }
}

// ---- one-time: enc_h -> fp16 plane of ring slot 0
__global__ void h0_kernel(const float* __restrict__ enc_h, unsigned short* __restrict__ hring) {
    int i = blockIdx.x * 256 + threadIdx.x;  // 0..65535
    hring[i] = f2h(enc_h[i]);
}

template <int RING, int GUARD, int FCAD>
__global__ void __launch_bounds__(512, 1)
lstm_kernel(const float* __restrict__ enc_c,
            const int* __restrict__ trg,
            const float* __restrict__ Ww,
            const float* __restrict__ Wb,
            const float* __restrict__ fcw,
            const float* __restrict__ fcb,
            const unsigned short* __restrict__ embT,
            unsigned short* __restrict__ hring,
            int* __restrict__ syn,
            float* __restrict__ out) {
    __shared__ unsigned short smw[65536];   // 128 KB: fp16 weight slice, XOR-swizzled
    __shared__ float gl[4][16][69];         // pre-acts [rowtile][row][col 0..63] (+pad)

    const int wg = blockIdx.x;
    const int tid = threadIdx.x;
    const int wv = tid >> 6;      // 0..7
    const int lane = tid & 63;
    const int rtp = wv >> 2;      // rt pair (rows rtp*32 .. +31)
    const int bth = (wv >> 1) & 1;// batch half
    const int kh = wv & 1;        // k half
    const int ml = lane & 15;
    const int kq = lane >> 4;
    const int kl8 = kq * 8;
    const int rq = kq * 4;
    int* gfl4 = syn;              // 64 gate epoch flags, packed 4B
    int* lfl4 = syn + 64;         // 16 logit progress flags, packed 4B

    if (wg < NGATE) {
        // ============ gate WG: hidden units [u0, u0+16), 4 gates ============
        const int u0 = wg * 16;
        for (int c = tid; c < 8192; c += 512) {   // 64 rows x 1024 fp16 -> LDS
            int row = c >> 7;
            int col8 = (c & 127) << 3;
            int grow = ((row >> 4) << 10) + u0 + (row & 15);   // q*1024 + u0 + uu
            const float* src = Ww + (size_t)grow * WROW + 1000 + col8;
            float4 a = *(const float4*)src;
            float4 b2 = *(const float4*)(src + 4);
            union { unsigned short us[8]; short8 s; } w;
            w.us[0] = f2h(a.x); w.us[1] = f2h(a.y); w.us[2] = f2h(a.z); w.us[3] = f2h(a.w);
            w.us[4] = f2h(b2.x); w.us[5] = f2h(b2.y); w.us[6] = f2h(b2.z); w.us[7] = f2h(b2.w);
            int byt = ((c & 127) << 4) ^ ((row & 7) << 4);
            *(short8*)(smw + (row << 10) + (byt >> 1)) = w.s;
        }
        const int b = tid & 63;       // pointwise role: batch
        const int q8 = tid >> 6;      // pointwise role: unit pair (0..7)
        float bs[4][2];
        #pragma unroll
        for (int q = 0; q < 4; ++q)
            #pragma unroll
            for (int j = 0; j < 2; ++j)
                bs[q][j] = Wb[(q << 10) + u0 + (q8 << 1) + j];
        float creg[2];                // cell state fp32, register-resident
        #pragma unroll
        for (int j = 0; j < 2; ++j)
            creg[j] = enc_c[(size_t)b * NH + u0 + (q8 << 1) + j];
        __syncthreads();

        for (int p = 1; p <= TT; ++p) {
            // embedding prefetch (plain cached loads; overlap the spin)
            int idx = trg[b * TT + p - 1];
            unsigned int emb[4];
            #pragma unroll
            for (int q = 0; q < 4; ++q)
                emb[q] = *(const unsigned int*)(embT + (size_t)idx * 4096 + (q << 10) + u0 + (q8 << 1));
            // wait: wave 0 only, packed-flag polls (coalesced sc1 loads, no RMW)
            if (tid < 64) {
                if (p > 1)
                    while (__hip_atomic_load(gfl4 + tid, __ATOMIC_RELAXED, AGT) < p - 1) { }
                if (p > GUARD && tid < NLOGIT)   // ring-reuse guard vs trailing logits
                    while (__hip_atomic_load(lfl4 + tid, __ATOMIC_RELAXED, AGT) < p - GUARD) { }
                if (FCAD == 1 || (p & (FCAD - 1)) == 1)  // staleness-bounding acquire
                    __builtin_amdgcn_fence(__ATOMIC_ACQUIRE, "agent");
            }
            __syncthreads();

            const unsigned short* hh = hring + (size_t)((p - 1) & (RING - 1)) * 65536;
            f32x4 acc[2][2] = {};
            #pragma unroll
            for (int j = 0; j < 16; ++j) {
                int kb = (((kh << 4) + j) << 5) + kl8;
                half8 bh0 = as_h8(*(const short8*)(hh + ((bth << 5) + ml) * NH + kb));
                half8 bh1 = as_h8(*(const short8*)(hh + ((bth << 5) + 16 + ml) * NH + kb));
                #pragma unroll
                for (int rr = 0; rr < 2; ++rr) {
                    int row = (((rtp << 1) + rr) << 4) + ml;
                    int byt = (kb << 1) ^ ((row & 7) << 4);
                    half8 a = as_h8(*(const short8*)(smw + (row << 10) + (byt >> 1)));
                    acc[rr][0] = __builtin_amdgcn_mfma_f32_16x16x32_f16(a, bh0, acc[rr][0], 0, 0, 0);
                    acc[rr][1] = __builtin_amdgcn_mfma_f32_16x16x32_f16(a, bh1, acc[rr][1], 0, 0, 0);
                }
            }
            // combine the two k-halves through gl
            if (kh) {
                #pragma unroll
                for (int rr = 0; rr < 2; ++rr)
                    #pragma unroll
                    for (int i = 0; i < 2; ++i)
                        #pragma unroll
                        for (int r = 0; r < 4; ++r)
                            gl[(rtp << 1) + rr][rq + r][(bth << 5) + (i << 4) + ml] = acc[rr][i][r];
            }
            __syncthreads();
            if (!kh) {
                #pragma unroll
                for (int rr = 0; rr < 2; ++rr)
                    #pragma unroll
                    for (int i = 0; i < 2; ++i)
                        #pragma unroll
                        for (int r = 0; r < 4; ++r)
                            gl[(rtp << 1) + rr][rq + r][(bth << 5) + (i << 4) + ml] += acc[rr][i][r];
            }
            __syncthreads();
            // pointwise: thread handles batch b, units q8*2..+1
            unsigned int hw = 0;
            #pragma unroll
            for (int j = 0; j < 2; ++j) {
                int u = (q8 << 1) + j;
                float pi = gl[0][u][b] + bs[0][j] + bf2f((unsigned short)(emb[0] >> (j * 16)));
                float pf = gl[1][u][b] + bs[1][j] + bf2f((unsigned short)(emb[1] >> (j * 16)));
                float pg = gl[2][u][b] + bs[2][j] + bf2f((unsigned short)(emb[2] >> (j * 16)));
                float po = gl[3][u][b] + bs[3][j] + bf2f((unsigned short)(emb[3] >> (j * 16)));
                float ii = sigm(pi), ff = sigm(pf), gg = tanh_f(pg), oo = sigm(po);
                float cc = ff * creg[j] + ii * gg;
                creg[j] = cc;
                float hv = oo * tanh_f(cc);
                hw |= (unsigned int)f2h(hv) << (j * 16);
            }
            unsigned short* nh = hring + (size_t)(p & (RING - 1)) * 65536;
            __hip_atomic_store((unsigned int*)(nh + (size_t)b * NH + u0 + (q8 << 1)),
                               hw, __ATOMIC_RELAXED, AGT);
            asm volatile("s_waitcnt vmcnt(0)" ::: "memory");  // h store at coherence point
            __syncthreads();
            if (tid == 0)
                __hip_atomic_store(gfl4 + wg, p, __ATOMIC_RELAXED, AGT);
        }
    } else {
        // ============ logit WG: vocab rows [v0, v0+64) ============
        const int lw = wg - NGATE;
        const int v0 = lw << 6;
        for (int c = tid; c < 8192; c += 512) {   // 64 rows of fc_w (fp16) -> LDS
            int row = c >> 7;
            int col8 = (c & 127) << 3;
            int grow = v0 + row; if (grow > NV - 1) grow = NV - 1;
            const float* src = fcw + (size_t)grow * NH + col8;
            float4 a = *(const float4*)src;
            float4 b2 = *(const float4*)(src + 4);
            union { unsigned short us[8]; short8 s; } w;
            w.us[0] = f2h(a.x); w.us[1] = f2h(a.y); w.us[2] = f2h(a.z); w.us[3] = f2h(a.w);
            w.us[4] = f2h(b2.x); w.us[5] = f2h(b2.y); w.us[6] = f2h(b2.z); w.us[7] = f2h(b2.w);
            int byt = ((c & 127) << 4) ^ ((row & 7) << 4);
            *(short8*)(smw + (row << 10) + (byt >> 1)) = w.s;
        }
        f32x4 fbv[2];
        #pragma unroll
        for (int rr = 0; rr < 2; ++rr)
            #pragma unroll
            for (int r = 0; r < 4; ++r) {
                int v = v0 + (((rtp << 1) + rr) << 4) + rq + r;
                fbv[rr][r] = fcb[v < NV ? v : NV - 1];
            }
        const int qq = tid & 15;     // store role: v quad (0..15)
        const int brow = tid >> 4;   // store role: batch row (0..31), 2 passes
        __syncthreads();

        for (int q = 1; q <= TT; ++q) {
            if (tid < 64) {
                while (__hip_atomic_load(gfl4 + tid, __ATOMIC_RELAXED, AGT) < q) { }
                if (FCAD == 1 || (q & (FCAD - 1)) == 1)
                    __builtin_amdgcn_fence(__ATOMIC_ACQUIRE, "agent");
            }
            __syncthreads();
            const unsigned short* hh = hring + (size_t)(q & (RING - 1)) * 65536;
            f32x4 acc[2][2] = {};
            #pragma unroll
            for (int j = 0; j < 16; ++j) {
                int kb = (((kh << 4) + j) << 5) + kl8;
                half8 bh0 = as_h8(*(const short8*)(hh + ((bth << 5) + ml) * NH + kb));
                half8 bh1 = as_h8(*(const short8*)(hh + ((bth << 5) + 16 + ml) * NH + kb));
                #pragma unroll
                for (int rr = 0; rr < 2; ++rr) {
                    int row = (((rtp << 1) + rr) << 4) + ml;
                    int byt = (kb << 1) ^ ((row & 7) << 4);
                    half8 a = as_h8(*(const short8*)(smw + (row << 10) + (byt >> 1)));
                    acc[rr][0] = __builtin_amdgcn_mfma_f32_16x16x32_f16(a, bh0, acc[rr][0], 0, 0, 0);
                    acc[rr][1] = __builtin_amdgcn_mfma_f32_16x16x32_f16(a, bh1, acc[rr][1], 0, 0, 0);
                }
            }
            if (kh) {
                #pragma unroll
                for (int rr = 0; rr < 2; ++rr)
                    #pragma unroll
                    for (int i = 0; i < 2; ++i)
                        #pragma unroll
                        for (int r = 0; r < 4; ++r)
                            gl[(rtp << 1) + rr][rq + r][(bth << 5) + (i << 4) + ml] = acc[rr][i][r];
            }
            __syncthreads();
            // all h reads complete (consumed into acc before the barrier):
            // release the ring slot NOW, off the store path.
            if (tid == 0)
                __hip_atomic_store(lfl4 + lw, q, __ATOMIC_RELAXED, AGT);
            // kh=0 finalizes into gl in-place (acc + gl + bias)
            if (!kh) {
                #pragma unroll
                for (int rr = 0; rr < 2; ++rr) {
                    int rt = (rtp << 1) + rr;
                    #pragma unroll
                    for (int i = 0; i < 2; ++i) {
                        int bb = (bth << 5) + (i << 4) + ml;
                        f32x4 v = acc[rr][i] + fbv[rr];
                        #pragma unroll
                        for (int r = 0; r < 4; ++r) v[r] += gl[rt][rq + r][bb];
                        #pragma unroll
                        for (int r = 0; r < 4; ++r) gl[rt][rq + r][bb] = v[r];
                    }
                }
            }
            __syncthreads();
            // transposed cooperative store: 16 lanes cover 256 contiguous B of one
            // out row -> full 64B lines, streaming (no RMW, no write-amp).
            #pragma unroll
            for (int pass = 0; pass < 2; ++pass) {
                int b2 = brow + (pass << 5);
                int vbase = v0 + (qq << 2);
                f32x4 val;
                #pragma unroll
                for (int r = 0; r < 4; ++r)
                    val[r] = gl[qq >> 2][((qq & 3) << 2) + r][b2];
                if (vbase + 3 < NV)
                    __builtin_nontemporal_store(val,
                        (f32x4*)(out + ((size_t)b2 * TT + (q - 1)) * NV + vbase));
            }
            __syncthreads();   // gl reuse guard for next iteration
        }
    }
}

extern "C" void kernel_launch(void* const* d_in, const int* in_sizes, int n_in,
                              void* d_out, int out_size, void* d_ws, size_t ws_size,
                              hipStream_t stream) {
    const float* enc_h = (const float*)d_in[0];
    const float* enc_c = (const float*)d_in[1];
    const int* trg = (const int*)d_in[2];
    const float* Ww = (const float*)d_in[3];
    const float* Wb = (const float*)d_in[4];
    const float* fcw = (const float*)d_in[5];
    const float* fcb = (const float*)d_in[6];
    float* out = (float*)d_out;

    unsigned short* embT = (unsigned short*)d_ws;        // 1000 x 4096 bf16 (8 MB)
    unsigned short* hring = embT + (size_t)1000 * 4096;  // RING slots x 128 KB (fp16)

    const size_t embBytes = (size_t)1000 * 4096 * 2;
    const size_t slotBytes = (size_t)65536 * 2;
    const size_t need16 = embBytes + 16 * slotBytes + 8192;  // ~10.3 MB

    hipLaunchKernelGGL(embT_kernel, dim3(1024), dim3(256), 0, stream, Ww, embT);
    hipLaunchKernelGGL(h0_kernel, dim3(256), dim3(256), 0, stream, enc_h, hring);

    if (ws_size >= need16) {
        int* syn = (int*)(hring + (size_t)16 * 65536);
        hipMemsetAsync(syn, 0, 8192, stream);
        lstm_kernel<16, 8, 8><<<dim3(NGATE + NLOGIT), dim3(512), 0, stream>>>(
            enc_c, trg, Ww, Wb, fcw, fcb, embT, hring, syn, out);
    } else {
        int* syn = (int*)(hring + (size_t)4 * 65536);
        hipMemsetAsync(syn, 0, 8192, stream);
        lstm_kernel<4, 4, 1><<<dim3(NGATE + NLOGIT), dim3(512), 0, stream>>>(
            enc_c, trg, Ww, Wb, fcw, fcb, embT, hring, syn, out);
    }
}

// Round 9
// 2310.038 us; speedup vs baseline: 1.4166x; 1.4166x over previous
//
#include <hip/hip_runtime.h>

// Persistent LSTM decoder, fence-lite cross-WG pipeline, fp16 datapath.
// 64 gate WGs (16 units x 4 gates) + 16 logit WGs (64 vocab rows).
// 512 thr / 8 waves: wave = (b-tile 0..3) x (k-half 0..1), NON-redundant h reads;
// each wave preloads its 16 h fragments to registers (latency overlapped), then
// runs 4 row-tiles x 16 j MFMAs. h exchanged as a single fp16 plane via sc1
// write-through stores (vmcnt(0)-acked before flag); consumers use PLAIN cached
// loads on a RING-deep slot ring + wave0-only agent acquire fence every FCAD
// steps (FCAD <= RING - GUARD + 1). Flags packed 4B. Logit slot release early.

#define TT 256
#define NH 1024
#define NV 1000
#define WROW 2024   // V + H
#define NGATE 64
#define NLOGIT 16

typedef __attribute__((ext_vector_type(8))) short short8;
typedef __attribute__((ext_vector_type(8))) _Float16 half8;
typedef __attribute__((ext_vector_type(4))) float f32x4;

#define AGT __HIP_MEMORY_SCOPE_AGENT

__device__ __forceinline__ unsigned short f2bf(float f) {
    unsigned int u = __float_as_uint(f);
    u += 0x7fffu + ((u >> 16) & 1u);
    return (unsigned short)(u >> 16);
}
__device__ __forceinline__ float bf2f(unsigned short s) {
    return __uint_as_float(((unsigned int)s) << 16);
}
__device__ __forceinline__ unsigned short f2h(float f) {
    return __builtin_bit_cast(unsigned short, (_Float16)f);
}
__device__ __forceinline__ half8 as_h8(short8 s) {
    return __builtin_bit_cast(half8, s);
}
__device__ __forceinline__ float sigm(float x) {
    return __builtin_amdgcn_rcpf(1.0f + __expf(-x));
}
__device__ __forceinline__ float tanh_f(float x) {
    return 2.0f * __builtin_amdgcn_rcpf(1.0f + __expf(-2.0f * x)) - 1.0f;
}

// ---- one-time: transpose-cast embedding block Ww[:, :V] -> embT[V][4096] bf16
__global__ void embT_kernel(const float* __restrict__ Ww, unsigned short* __restrict__ embT) {
    __shared__ unsigned short tile[64][80];
    const int rt = blockIdx.x & 63, vt = blockIdx.x >> 6;
    const int r0 = rt * 64, v0 = vt * 64;
    const int t = threadIdx.x;
    {
        int rr = t >> 2, c0 = (t & 3) * 16;
        for (int j = 0; j < 16; ++j) {
            int v = v0 + c0 + j;
            float x = (v < NV) ? Ww[(size_t)(r0 + rr) * WROW + v] : 0.f;
            tile[c0 + j][rr] = f2bf(x);
        }
    }
    __syncthreads();
    {
        int vv = t >> 2, k0 = (t & 3) * 16;
        int v = v0 + vv;
        if (v < NV)
            for (int j = 0; j < 16; ++j)
                embT[(size_t)v * 4096 + r0 + k0 + j] = tile[vv][k0 + j];
    }
}

// ---- one-time: enc_h -> fp16 plane of ring slot 0
__global__ void h0_kernel(const float* __restrict__ enc_h, unsigned short* __restrict__ hring) {
    int i = blockIdx.x * 256 + threadIdx.x;  // 0..65535
    hring[i] = f2h(enc_h[i]);
}

template <int RING, int GUARD, int FCAD>
__global__ void __launch_bounds__(512, 1)
lstm_kernel(const float* __restrict__ enc_c,
            const int* __restrict__ trg,
            const float* __restrict__ Ww,
            const float* __restrict__ Wb,
            const float* __restrict__ fcw,
            const float* __restrict__ fcb,
            const unsigned short* __restrict__ embT,
            unsigned short* __restrict__ hring,
            int* __restrict__ syn,
            float* __restrict__ out) {
    __shared__ unsigned short smw[65536];   // 128 KB: fp16 weight slice, XOR-swizzled
    __shared__ float gl[4][16][68];         // pre-acts [rowtile][row][col 0..63]

    const int wg = blockIdx.x;
    const int tid = threadIdx.x;
    const int wv = tid >> 6;      // 0..7
    const int lane = tid & 63;
    const int bt = wv >> 1;       // b-tile 0..3 (batch rows bt*16..+15)
    const int kh = wv & 1;        // k-half (kt 0..15 / 16..31)
    const int ml = lane & 15;
    const int kq = lane >> 4;
    const int kl8 = kq * 8;
    const int rq = kq * 4;
    int* gfl4 = syn;              // 64 gate epoch flags, packed 4B
    int* lfl4 = syn + 64;         // 16 logit progress flags, packed 4B

    if (wg < NGATE) {
        // ============ gate WG: hidden units [u0, u0+16), 4 gates ============
        const int u0 = wg * 16;
        for (int c = tid; c < 8192; c += 512) {   // 64 rows x 1024 fp16 -> LDS
            int row = c >> 7;
            int col8 = (c & 127) << 3;
            int grow = ((row >> 4) << 10) + u0 + (row & 15);   // q*1024 + u0 + uu
            const float* src = Ww + (size_t)grow * WROW + 1000 + col8;
            float4 a = *(const float4*)src;
            float4 b2 = *(const float4*)(src + 4);
            union { unsigned short us[8]; short8 s; } w;
            w.us[0] = f2h(a.x); w.us[1] = f2h(a.y); w.us[2] = f2h(a.z); w.us[3] = f2h(a.w);
            w.us[4] = f2h(b2.x); w.us[5] = f2h(b2.y); w.us[6] = f2h(b2.z); w.us[7] = f2h(b2.w);
            int byt = ((c & 127) << 4) ^ ((row & 7) << 4);
            *(short8*)(smw + (row << 10) + (byt >> 1)) = w.s;
        }
        const int b = tid & 63;       // pointwise role: batch
        const int q8 = tid >> 6;      // pointwise role: unit pair (0..7)
        float bs[4][2];
        #pragma unroll
        for (int q = 0; q < 4; ++q)
            #pragma unroll
            for (int j = 0; j < 2; ++j)
                bs[q][j] = Wb[(q << 10) + u0 + (q8 << 1) + j];
        float creg[2];                // cell state fp32, register-resident
        #pragma unroll
        for (int j = 0; j < 2; ++j)
            creg[j] = enc_c[(size_t)b * NH + u0 + (q8 << 1) + j];
        __syncthreads();

        for (int p = 1; p <= TT; ++p) {
            // embedding prefetch (plain cached loads; overlap the spin)
            int idx = trg[b * TT + p - 1];
            unsigned int emb[4];
            #pragma unroll
            for (int q = 0; q < 4; ++q)
                emb[q] = *(const unsigned int*)(embT + (size_t)idx * 4096 + (q << 10) + u0 + (q8 << 1));
            // wait: wave 0 only, packed-flag polls (coalesced sc1 loads, no RMW)
            if (tid < 64) {
                if (p > 1)
                    while (__hip_atomic_load(gfl4 + tid, __ATOMIC_RELAXED, AGT) < p - 1) { }
                if (p > GUARD && tid < NLOGIT)   // ring-reuse guard vs trailing logits
                    while (__hip_atomic_load(lfl4 + tid, __ATOMIC_RELAXED, AGT) < p - GUARD) { }
                if (FCAD == 1 || (p & (FCAD - 1)) == 1)  // staleness-bounding acquire
                    __builtin_amdgcn_fence(__ATOMIC_ACQUIRE, "agent");
            }
            __syncthreads();

            const unsigned short* hh = hring + (size_t)((p - 1) & (RING - 1)) * 65536;
            // preload this wave's 16 h fragments -> registers (latency overlapped)
            half8 hb[16];
            #pragma unroll
            for (int j = 0; j < 16; ++j)
                hb[j] = as_h8(*(const short8*)(hh + ((bt << 4) + ml) * NH
                                               + (((kh << 4) + j) << 5) + kl8));
            f32x4 acc[4] = {};
            #pragma unroll
            for (int j = 0; j < 16; ++j) {
                int kb = (((kh << 4) + j) << 5) + kl8;
                #pragma unroll
                for (int rt = 0; rt < 4; ++rt) {
                    int row = (rt << 4) + ml;
                    int byt = (kb << 1) ^ ((row & 7) << 4);
                    half8 a = as_h8(*(const short8*)(smw + (row << 10) + (byt >> 1)));
                    acc[rt] = __builtin_amdgcn_mfma_f32_16x16x32_f16(a, hb[j], acc[rt], 0, 0, 0);
                }
            }
            // combine the two k-halves through gl
            if (kh) {
                #pragma unroll
                for (int rt = 0; rt < 4; ++rt)
                    #pragma unroll
                    for (int r = 0; r < 4; ++r)
                        gl[rt][rq + r][(bt << 4) + ml] = acc[rt][r];
            }
            __syncthreads();
            if (!kh) {
                #pragma unroll
                for (int rt = 0; rt < 4; ++rt)
                    #pragma unroll
                    for (int r = 0; r < 4; ++r)
                        gl[rt][rq + r][(bt << 4) + ml] += acc[rt][r];
            }
            __syncthreads();
            // pointwise: thread handles batch b, units q8*2..+1
            unsigned int hw = 0;
            #pragma unroll
            for (int j = 0; j < 2; ++j) {
                int u = (q8 << 1) + j;
                float pi = gl[0][u][b] + bs[0][j] + bf2f((unsigned short)(emb[0] >> (j * 16)));
                float pf = gl[1][u][b] + bs[1][j] + bf2f((unsigned short)(emb[1] >> (j * 16)));
                float pg = gl[2][u][b] + bs[2][j] + bf2f((unsigned short)(emb[2] >> (j * 16)));
                float po = gl[3][u][b] + bs[3][j] + bf2f((unsigned short)(emb[3] >> (j * 16)));
                float ii = sigm(pi), ff = sigm(pf), gg = tanh_f(pg), oo = sigm(po);
                float cc = ff * creg[j] + ii * gg;
                creg[j] = cc;
                float hv = oo * tanh_f(cc);
                hw |= (unsigned int)f2h(hv) << (j * 16);
            }
            unsigned short* nh = hring + (size_t)(p & (RING - 1)) * 65536;
            __hip_atomic_store((unsigned int*)(nh + (size_t)b * NH + u0 + (q8 << 1)),
                               hw, __ATOMIC_RELAXED, AGT);
            asm volatile("s_waitcnt vmcnt(0)" ::: "memory");  // h store at coherence point
            __syncthreads();
            if (tid == 0)
                __hip_atomic_store(gfl4 + wg, p, __ATOMIC_RELAXED, AGT);
        }
    } else {
        // ============ logit WG: vocab rows [v0, v0+64) ============
        const int lw = wg - NGATE;
        const int v0 = lw << 6;
        for (int c = tid; c < 8192; c += 512) {   // 64 rows of fc_w (fp16) -> LDS
            int row = c >> 7;
            int col8 = (c & 127) << 3;
            int grow = v0 + row; if (grow > NV - 1) grow = NV - 1;
            const float* src = fcw + (size_t)grow * NH + col8;
            float4 a = *(const float4*)src;
            float4 b2 = *(const float4*)(src + 4);
            union { unsigned short us[8]; short8 s; } w;
            w.us[0] = f2h(a.x); w.us[1] = f2h(a.y); w.us[2] = f2h(a.z); w.us[3] = f2h(a.w);
            w.us[4] = f2h(b2.x); w.us[5] = f2h(b2.y); w.us[6] = f2h(b2.z); w.us[7] = f2h(b2.w);
            int byt = ((c & 127) << 4) ^ ((row & 7) << 4);
            *(short8*)(smw + (row << 10) + (byt >> 1)) = w.s;
        }
        f32x4 fbv[4];
        #pragma unroll
        for (int rt = 0; rt < 4; ++rt)
            #pragma unroll
            for (int r = 0; r < 4; ++r) {
                int v = v0 + (rt << 4) + rq + r;
                fbv[rt][r] = fcb[v < NV ? v : NV - 1];
            }
        __syncthreads();

        for (int q = 1; q <= TT; ++q) {
            if (tid < 64) {
                while (__hip_atomic_load(gfl4 + tid, __ATOMIC_RELAXED, AGT) < q) { }
                if (FCAD == 1 || (q & (FCAD - 1)) == 1)
                    __builtin_amdgcn_fence(__ATOMIC_ACQUIRE, "agent");
            }
            __syncthreads();
            const unsigned short* hh = hring + (size_t)(q & (RING - 1)) * 65536;
            half8 hb[16];
            #pragma unroll
            for (int j = 0; j < 16; ++j)
                hb[j] = as_h8(*(const short8*)(hh + ((bt << 4) + ml) * NH
                                               + (((kh << 4) + j) << 5) + kl8));
            f32x4 acc[4] = {};
            #pragma unroll
            for (int j = 0; j < 16; ++j) {
                int kb = (((kh << 4) + j) << 5) + kl8;
                #pragma unroll
                for (int rt = 0; rt < 4; ++rt) {
                    int row = (rt << 4) + ml;
                    int byt = (kb << 1) ^ ((row & 7) << 4);
                    half8 a = as_h8(*(const short8*)(smw + (row << 10) + (byt >> 1)));
                    acc[rt] = __builtin_amdgcn_mfma_f32_16x16x32_f16(a, hb[j], acc[rt], 0, 0, 0);
                }
            }
            if (kh) {
                #pragma unroll
                for (int rt = 0; rt < 4; ++rt)
                    #pragma unroll
                    for (int r = 0; r < 4; ++r)
                        gl[rt][rq + r][(bt << 4) + ml] = acc[rt][r];
            }
            __syncthreads();
            // h fully consumed: release slot NOW (before the out stores)
            if (tid == 0)
                __hip_atomic_store(lfl4 + lw, q, __ATOMIC_RELAXED, AGT);
            if (!kh) {
                int bb = (bt << 4) + ml;
                #pragma unroll
                for (int rt = 0; rt < 4; ++rt) {
                    int vq = v0 + (rt << 4) + rq;
                    f32x4 v = acc[rt] + fbv[rt];
                    #pragma unroll
                    for (int r = 0; r < 4; ++r) v[r] += gl[rt][rq + r][bb];
                    if (vq + 3 < NV) {
                        // sc1 write-through stores: never dirty-in-L2 (inv-safe)
                        union { f32x4 v; unsigned long long u[2]; } cv; cv.v = v;
                        unsigned long long* po =
                            (unsigned long long*)(out + ((size_t)bb * TT + (q - 1)) * NV + vq);
                        __hip_atomic_store(po, cv.u[0], __ATOMIC_RELAXED, AGT);
                        __hip_atomic_store(po + 1, cv.u[1], __ATOMIC_RELAXED, AGT);
                    }
                }
            }
            __syncthreads();   // gl reuse guard for next iteration (no vmcnt drain)
        }
    }
}

extern "C" void kernel_launch(void* const* d_in, const int* in_sizes, int n_in,
                              void* d_out, int out_size, void* d_ws, size_t ws_size,
                              hipStream_t stream) {
    const float* enc_h = (const float*)d_in[0];
    const float* enc_c = (const float*)d_in[1];
    const int* trg = (const int*)d_in[2];
    const float* Ww = (const float*)d_in[3];
    const float* Wb = (const float*)d_in[4];
    const float* fcw = (const float*)d_in[5];
    const float* fcb = (const float*)d_in[6];
    float* out = (float*)d_out;

    unsigned short* embT = (unsigned short*)d_ws;        // 1000 x 4096 bf16 (8 MB)
    unsigned short* hring = embT + (size_t)1000 * 4096;  // RING slots x 128 KB (fp16)

    const size_t embBytes = (size_t)1000 * 4096 * 2;
    const size_t slotBytes = (size_t)65536 * 2;
    const size_t need16 = embBytes + 16 * slotBytes + 8192;  // ~10.3 MB

    hipLaunchKernelGGL(embT_kernel, dim3(1024), dim3(256), 0, stream, Ww, embT);
    hipLaunchKernelGGL(h0_kernel, dim3(256), dim3(256), 0, stream, enc_h, hring);

    if (ws_size >= need16) {
        int* syn = (int*)(hring + (size_t)16 * 65536);
        hipMemsetAsync(syn, 0, 8192, stream);
        lstm_kernel<16, 8, 8><<<dim3(NGATE + NLOGIT), dim3(512), 0, stream>>>(
            enc_c, trg, Ww, Wb, fcw, fcb, embT, hring, syn, out);
    } else {
        int* syn = (int*)(hring + (size_t)4 * 65536);
        hipMemsetAsync(syn, 0, 8192, stream);
        lstm_kernel<4, 4, 1><<<dim3(NGATE + NLOGIT), dim3(512), 0, stream>>>(
            enc_c, trg, Ww, Wb, fcw, fcb, embT, hring, syn, out);
    }
}

// Round 10
// 2212.516 us; speedup vs baseline: 1.4790x; 1.0441x over previous
//
#include <hip/hip_runtime.h>

// Persistent LSTM decoder, FUSED gate+logit WGs, fp16 datapath.
// 64 WGs x 512 thr (8 waves: b-tile x k-half). Each WG owns 16 hidden units
// (4 gate rows each, weights in LDS) AND 16 vocab rows (fc weights in REGISTERS
// as MFMA A-fragments). Per step: one shared h load feeds both gate and logit
// MFMAs; h store + flag release FIRST, logit finish + out stores AFTER (off the
// critical path). h via sc1 write-through stores (vmcnt(0)-acked before flag);
// consumers PLAIN cached loads on RING slots + wave0 acquire fence every FCAD
// steps (skew<=1, RING>=4 -> staleness bounded). Flags packed 4B, no RMW.

#define TT 256
#define NH 1024
#define NV 1000
#define WROW 2024   // V + H
#define NWG 64

typedef __attribute__((ext_vector_type(8))) short short8;
typedef __attribute__((ext_vector_type(8))) _Float16 half8;
typedef __attribute__((ext_vector_type(4))) float f32x4;

#define AGT __HIP_MEMORY_SCOPE_AGENT

__device__ __forceinline__ unsigned short f2bf(float f) {
    unsigned int u = __float_as_uint(f);
    u += 0x7fffu + ((u >> 16) & 1u);
    return (unsigned short)(u >> 16);
}
__device__ __forceinline__ float bf2f(unsigned short s) {
    return __uint_as_float(((unsigned int)s) << 16);
}
__device__ __forceinline__ unsigned short f2h(float f) {
    return __builtin_bit_cast(unsigned short, (_Float16)f);
}
__device__ __forceinline__ half8 as_h8(short8 s) {
    return __builtin_bit_cast(half8, s);
}
__device__ __forceinline__ float sigm(float x) {
    return __builtin_amdgcn_rcpf(1.0f + __expf(-x));
}
__device__ __forceinline__ float tanh_f(float x) {
    return 2.0f * __builtin_amdgcn_rcpf(1.0f + __expf(-2.0f * x)) - 1.0f;
}

// ---- one-time: transpose-cast embedding block Ww[:, :V] -> embT[V][4096] bf16
__global__ void embT_kernel(const float* __restrict__ Ww, unsigned short* __restrict__ embT) {
    __shared__ unsigned short tile[64][80];
    const int rt = blockIdx.x & 63, vt = blockIdx.x >> 6;
    const int r0 = rt * 64, v0 = vt * 64;
    const int t = threadIdx.x;
    {
        int rr = t >> 2, c0 = (t & 3) * 16;
        for (int j = 0; j < 16; ++j) {
            int v = v0 + c0 + j;
            float x = (v < NV) ? Ww[(size_t)(r0 + rr) * WROW + v] : 0.f;
            tile[c0 + j][rr] = f2bf(x);
        }
    }
    __syncthreads();
    {
        int vv = t >> 2, k0 = (t & 3) * 16;
        int v = v0 + vv;
        if (v < NV)
            for (int j = 0; j < 16; ++j)
                embT[(size_t)v * 4096 + r0 + k0 + j] = tile[vv][k0 + j];
    }
}

// ---- one-time: enc_h -> fp16 plane of ring slot 0
__global__ void h0_kernel(const float* __restrict__ enc_h, unsigned short* __restrict__ hring) {
    int i = blockIdx.x * 256 + threadIdx.x;  // 0..65535
    hring[i] = f2h(enc_h[i]);
}

template <int RING, int FCAD>
__global__ void __launch_bounds__(512, 2)
lstm_kernel(const float* __restrict__ enc_c,
            const int* __restrict__ trg,
            const float* __restrict__ Ww,
            const float* __restrict__ Wb,
            const float* __restrict__ fcw,
            const float* __restrict__ fcb,
            const unsigned short* __restrict__ embT,
            unsigned short* __restrict__ hring,
            int* __restrict__ syn,
            float* __restrict__ out) {
    __shared__ unsigned short smw[65536];   // 128 KB: fp16 gate weights, XOR-swizzled
    __shared__ float gl[4][16][68];         // pre-acts [rowtile][row][col 0..63]

    const int wg = blockIdx.x;
    const int tid = threadIdx.x;
    const int wv = tid >> 6;      // 0..7
    const int lane = tid & 63;
    const int bt = wv >> 1;       // b-tile 0..3 (batch rows bt*16..+15)
    const int kh = wv & 1;        // k-half (kt 0..15 / 16..31)
    const int ml = lane & 15;
    const int kq = lane >> 4;
    const int kl8 = kq * 8;
    const int rq = kq * 4;
    int* gfl4 = syn;              // 64 epoch flags, packed 4B

    // ============ init: gate weights -> LDS ============
    const int u0 = wg * 16;       // hidden units [u0, u0+16)
    for (int c = tid; c < 8192; c += 512) {   // 64 rows x 1024 fp16 -> LDS
        int row = c >> 7;
        int col8 = (c & 127) << 3;
        int grow = ((row >> 4) << 10) + u0 + (row & 15);   // q*1024 + u0 + uu
        const float* src = Ww + (size_t)grow * WROW + 1000 + col8;
        float4 a = *(const float4*)src;
        float4 b2 = *(const float4*)(src + 4);
        union { unsigned short us[8]; short8 s; } w;
        w.us[0] = f2h(a.x); w.us[1] = f2h(a.y); w.us[2] = f2h(a.z); w.us[3] = f2h(a.w);
        w.us[4] = f2h(b2.x); w.us[5] = f2h(b2.y); w.us[6] = f2h(b2.z); w.us[7] = f2h(b2.w);
        int byt = ((c & 127) << 4) ^ ((row & 7) << 4);
        *(short8*)(smw + (row << 10) + (byt >> 1)) = w.s;
    }
    // ============ init: logit fc rows [v0, v0+16) -> registers (A-fragments) ============
    const int v0 = wg * 16;
    const int vrowc = (v0 + ml < NV) ? v0 + ml : NV - 1;
    half8 la[16];
    #pragma unroll
    for (int j = 0; j < 16; ++j) {
        const float* src = fcw + (size_t)vrowc * NH + (kh << 9) + (j << 5) + kl8;
        union { unsigned short us[8]; short8 s; } w;
        #pragma unroll
        for (int e = 0; e < 8; ++e) w.us[e] = f2h(src[e]);
        la[j] = as_h8(w.s);
    }
    f32x4 fbv;
    #pragma unroll
    for (int r = 0; r < 4; ++r) {
        int v = v0 + rq + r;
        fbv[r] = fcb[v < NV ? v : NV - 1];
    }
    // pointwise roles
    const int b = tid & 63;       // batch
    const int q8 = tid >> 6;      // unit pair (0..7)
    float bs[4][2];
    #pragma unroll
    for (int q = 0; q < 4; ++q)
        #pragma unroll
        for (int j = 0; j < 2; ++j)
            bs[q][j] = Wb[(q << 10) + u0 + (q8 << 1) + j];
    float creg[2];                // cell state fp32, register-resident
    #pragma unroll
    for (int j = 0; j < 2; ++j)
        creg[j] = enc_c[(size_t)b * NH + u0 + (q8 << 1) + j];
    __syncthreads();

    for (int p = 1; p <= TT + 1; ++p) {
        // embedding prefetch (plain cached loads; overlap the spin)
        unsigned int emb[4];
        if (p <= TT) {
            int idx = trg[b * TT + p - 1];
            #pragma unroll
            for (int q = 0; q < 4; ++q)
                emb[q] = *(const unsigned int*)(embT + (size_t)idx * 4096 + (q << 10) + u0 + (q8 << 1));
        }
        // wait: wave 0 only, packed-flag polls (coalesced sc1 loads, no RMW)
        if (tid < 64) {
            if (p > 1)
                while (__hip_atomic_load(gfl4 + tid, __ATOMIC_RELAXED, AGT) < p - 1) { }
            if (FCAD == 1 || (p & (FCAD - 1)) == 1)  // staleness-bounding acquire
                __builtin_amdgcn_fence(__ATOMIC_ACQUIRE, "agent");
        }
        __syncthreads();

        const unsigned short* hh = hring + (size_t)((p - 1) & (RING - 1)) * 65536;
        // ONE shared h preload feeds both gate and logit MFMAs
        half8 hb[16];
        #pragma unroll
        for (int j = 0; j < 16; ++j)
            hb[j] = as_h8(*(const short8*)(hh + ((bt << 4) + ml) * NH
                                           + (((kh << 4) + j) << 5) + kl8));

        // ---------------- gate phase (critical path) ----------------
        if (p <= TT) {
            f32x4 acc[4] = {};
            #pragma unroll
            for (int j = 0; j < 16; ++j) {
                int kb = (((kh << 4) + j) << 5) + kl8;
                #pragma unroll
                for (int rt = 0; rt < 4; ++rt) {
                    int row = (rt << 4) + ml;
                    int byt = (kb << 1) ^ ((row & 7) << 4);
                    half8 a = as_h8(*(const short8*)(smw + (row << 10) + (byt >> 1)));
                    acc[rt] = __builtin_amdgcn_mfma_f32_16x16x32_f16(a, hb[j], acc[rt], 0, 0, 0);
                }
            }
            if (kh) {
                #pragma unroll
                for (int rt = 0; rt < 4; ++rt)
                    #pragma unroll
                    for (int r = 0; r < 4; ++r)
                        gl[rt][rq + r][(bt << 4) + ml] = acc[rt][r];
            }
            __syncthreads();
            if (!kh) {
                #pragma unroll
                for (int rt = 0; rt < 4; ++rt)
                    #pragma unroll
                    for (int r = 0; r < 4; ++r)
                        gl[rt][rq + r][(bt << 4) + ml] += acc[rt][r];
            }
            __syncthreads();
            // pointwise: thread handles batch b, units q8*2..+1
            unsigned int hw = 0;
            #pragma unroll
            for (int j = 0; j < 2; ++j) {
                int u = (q8 << 1) + j;
                float pi = gl[0][u][b] + bs[0][j] + bf2f((unsigned short)(emb[0] >> (j * 16)));
                float pf = gl[1][u][b] + bs[1][j] + bf2f((unsigned short)(emb[1] >> (j * 16)));
                float pg = gl[2][u][b] + bs[2][j] + bf2f((unsigned short)(emb[2] >> (j * 16)));
                float po = gl[3][u][b] + bs[3][j] + bf2f((unsigned short)(emb[3] >> (j * 16)));
                float ii = sigm(pi), ff = sigm(pf), gg = tanh_f(pg), oo = sigm(po);
                float cc = ff * creg[j] + ii * gg;
                creg[j] = cc;
                float hv = oo * tanh_f(cc);
                hw |= (unsigned int)f2h(hv) << (j * 16);
            }
            unsigned short* nh = hring + (size_t)(p & (RING - 1)) * 65536;
            __hip_atomic_store((unsigned int*)(nh + (size_t)b * NH + u0 + (q8 << 1)),
                               hw, __ATOMIC_RELAXED, AGT);
            asm volatile("s_waitcnt vmcnt(0)" ::: "memory");  // h store at coherence point
            __syncthreads();
            if (tid == 0)
                __hip_atomic_store(gfl4 + wg, p, __ATOMIC_RELAXED, AGT);  // RELEASE the step
        }

        // ---------------- logit phase for t = p-2 (off the critical path) ----------------
        if (p >= 2) {
            f32x4 accl = {};
            #pragma unroll
            for (int j = 0; j < 16; ++j)
                accl = __builtin_amdgcn_mfma_f32_16x16x32_f16(la[j], hb[j], accl, 0, 0, 0);
            if (kh) {
                #pragma unroll
                for (int r = 0; r < 4; ++r)
                    gl[0][rq + r][(bt << 4) + ml] = accl[r];
            }
            __syncthreads();
            if (!kh) {
                int bb = (bt << 4) + ml;
                f32x4 v = accl + fbv;
                #pragma unroll
                for (int r = 0; r < 4; ++r) v[r] += gl[0][rq + r][bb];
                int vq = v0 + rq;
                float* po = out + ((size_t)bb * TT + (p - 2)) * NV + vq;
                if (vq + 3 < NV) {
                    // sc1 write-through stores: never dirty-in-L2 (inv-safe)
                    union { f32x4 v; unsigned long long u[2]; } cv; cv.v = v;
                    __hip_atomic_store((unsigned long long*)po, cv.u[0], __ATOMIC_RELAXED, AGT);
                    __hip_atomic_store((unsigned long long*)po + 1, cv.u[1], __ATOMIC_RELAXED, AGT);
                } else {
                    #pragma unroll
                    for (int r = 0; r < 4; ++r)
                        if (vq + r < NV)
                            __hip_atomic_store((unsigned int*)(po + r),
                                               __builtin_bit_cast(unsigned int, v[r]),
                                               __ATOMIC_RELAXED, AGT);
                }
            }
            __syncthreads();   // gl reuse guard for next iteration
        }
    }
}

extern "C" void kernel_launch(void* const* d_in, const int* in_sizes, int n_in,
                              void* d_out, int out_size, void* d_ws, size_t ws_size,
                              hipStream_t stream) {
    const float* enc_h = (const float*)d_in[0];
    const float* enc_c = (const float*)d_in[1];
    const int* trg = (const int*)d_in[2];
    const float* Ww = (const float*)d_in[3];
    const float* Wb = (const float*)d_in[4];
    const float* fcw = (const float*)d_in[5];
    const float* fcb = (const float*)d_in[6];
    float* out = (float*)d_out;

    unsigned short* embT = (unsigned short*)d_ws;        // 1000 x 4096 bf16 (8 MB)
    unsigned short* hring = embT + (size_t)1000 * 4096;  // RING slots x 128 KB (fp16)

    const size_t embBytes = (size_t)1000 * 4096 * 2;
    const size_t slotBytes = (size_t)65536 * 2;
    const size_t need16 = embBytes + 16 * slotBytes + 8192;  // ~10.3 MB

    hipLaunchKernelGGL(embT_kernel, dim3(1024), dim3(256), 0, stream, Ww, embT);
    hipLaunchKernelGGL(h0_kernel, dim3(256), dim3(256), 0, stream, enc_h, hring);

    if (ws_size >= need16) {
        int* syn = (int*)(hring + (size_t)16 * 65536);
        hipMemsetAsync(syn, 0, 4096, stream);
        lstm_kernel<16, 8><<<dim3(NWG), dim3(512), 0, stream>>>(
            enc_c, trg, Ww, Wb, fcw, fcb, embT, hring, syn, out);
    } else {
        int* syn = (int*)(hring + (size_t)4 * 65536);
        hipMemsetAsync(syn, 0, 4096, stream);
        lstm_kernel<4, 1><<<dim3(NWG), dim3(512), 0, stream>>>(
            enc_c, trg, Ww, Wb, fcw, fcb, embT, hring, syn, out);
    }
}

// Round 11
// 1527.884 us; speedup vs baseline: 2.1417x; 1.4481x over previous
//
#include <hip/hip_runtime.h>

// Persistent LSTM decoder, FUSED gate+logit WGs, fp16 datapath, coalesced stores.
// 64 WGs x 512 thr (8 waves: b-tile x k-half). Each WG owns 16 hidden units
// (gate weights in LDS) AND 16 vocab rows (fc weights in registers).
// h ring layout is per-WG BLOCKED: [slot][block=64][b=64][u=16] fp16 -> each WG
// stores one contiguous 2KB block (LDS-staged, 128x16B coalesced sc1 stores);
// consumers read contiguous 2KB blocks (same MFMA fragments as before).
// Out: finalize into LDS tile, 256x aligned 16B nontemporal full-line stores,
// drain deferred under the next step's flag spin (no trailing barrier).
// Sync skeleton unchanged: packed 4B flags, vmcnt(0)-acked h stores, wave0
// acquire fence every FCAD steps (FCAD <= RING-1 with skew<=1).

#define TT 256
#define NH 1024
#define NV 1000
#define WROW 2024   // V + H
#define NWG 64

typedef __attribute__((ext_vector_type(8))) short short8;
typedef __attribute__((ext_vector_type(8))) _Float16 half8;
typedef __attribute__((ext_vector_type(4))) float f32x4;

#define AGT __HIP_MEMORY_SCOPE_AGENT

__device__ __forceinline__ unsigned short f2bf(float f) {
    unsigned int u = __float_as_uint(f);
    u += 0x7fffu + ((u >> 16) & 1u);
    return (unsigned short)(u >> 16);
}
__device__ __forceinline__ float bf2f(unsigned short s) {
    return __uint_as_float(((unsigned int)s) << 16);
}
__device__ __forceinline__ unsigned short f2h(float f) {
    return __builtin_bit_cast(unsigned short, (_Float16)f);
}
__device__ __forceinline__ half8 as_h8(short8 s) {
    return __builtin_bit_cast(half8, s);
}
__device__ __forceinline__ float sigm(float x) {
    return __builtin_amdgcn_rcpf(1.0f + __expf(-x));
}
__device__ __forceinline__ float tanh_f(float x) {
    return 2.0f * __builtin_amdgcn_rcpf(1.0f + __expf(-2.0f * x)) - 1.0f;
}

// ---- one-time: transpose-cast embedding block Ww[:, :V] -> embT[V][4096] bf16
__global__ void embT_kernel(const float* __restrict__ Ww, unsigned short* __restrict__ embT) {
    __shared__ unsigned short tile[64][80];
    const int rt = blockIdx.x & 63, vt = blockIdx.x >> 6;
    const int r0 = rt * 64, v0 = vt * 64;
    const int t = threadIdx.x;
    {
        int rr = t >> 2, c0 = (t & 3) * 16;
        for (int j = 0; j < 16; ++j) {
            int v = v0 + c0 + j;
            float x = (v < NV) ? Ww[(size_t)(r0 + rr) * WROW + v] : 0.f;
            tile[c0 + j][rr] = f2bf(x);
        }
    }
    __syncthreads();
    {
        int vv = t >> 2, k0 = (t & 3) * 16;
        int v = v0 + vv;
        if (v < NV)
            for (int j = 0; j < 16; ++j)
                embT[(size_t)v * 4096 + r0 + k0 + j] = tile[vv][k0 + j];
    }
}

// ---- one-time: enc_h -> fp16 blocked plane of ring slot 0 ([blk][b][u])
__global__ void h0_kernel(const float* __restrict__ enc_h, unsigned short* __restrict__ hring) {
    int i = blockIdx.x * 256 + threadIdx.x;  // 0..65535 over [64 b][1024 u]
    int b = i >> 10, u = i & 1023;
    hring[((u >> 4) << 10) + (b << 4) + (u & 15)] = f2h(enc_h[i]);
}

template <int RING, int FCAD>
__global__ void __launch_bounds__(512, 2)
lstm_kernel(const float* __restrict__ enc_c,
            const int* __restrict__ trg,
            const float* __restrict__ Ww,
            const float* __restrict__ Wb,
            const float* __restrict__ fcw,
            const float* __restrict__ fcb,
            const unsigned short* __restrict__ embT,
            unsigned short* __restrict__ hring,
            int* __restrict__ syn,
            float* __restrict__ out) {
    __shared__ unsigned short smw[65536];   // 128 KB: fp16 gate weights, XOR-swizzled
    __shared__ float gl[4][16][66];         // pre-acts; stride 66 -> uniform 2-way banks
    __shared__ unsigned short ht[64][20];   // h staging tile [b][u] (+pad)
    __shared__ float ot[64][17];            // logit staging tile [b][v-col] (+pad)

    const int wg = blockIdx.x;
    const int tid = threadIdx.x;
    const int wv = tid >> 6;      // 0..7
    const int lane = tid & 63;
    const int bt = wv >> 1;       // b-tile 0..3 (batch rows bt*16..+15)
    const int kh = wv & 1;        // k-half (kt 0..15 / 16..31)
    const int ml = lane & 15;
    const int kq = lane >> 4;
    const int kl8 = kq * 8;
    const int rq = kq * 4;
    int* gfl4 = syn;              // 64 epoch flags, packed 4B

    // ============ init: gate weights -> LDS ============
    const int u0 = wg * 16;       // hidden units [u0, u0+16)
    for (int c = tid; c < 8192; c += 512) {   // 64 rows x 1024 fp16 -> LDS
        int row = c >> 7;
        int col8 = (c & 127) << 3;
        int grow = ((row >> 4) << 10) + u0 + (row & 15);   // q*1024 + u0 + uu
        const float* src = Ww + (size_t)grow * WROW + 1000 + col8;
        float4 a = *(const float4*)src;
        float4 b2 = *(const float4*)(src + 4);
        union { unsigned short us[8]; short8 s; } w;
        w.us[0] = f2h(a.x); w.us[1] = f2h(a.y); w.us[2] = f2h(a.z); w.us[3] = f2h(a.w);
        w.us[4] = f2h(b2.x); w.us[5] = f2h(b2.y); w.us[6] = f2h(b2.z); w.us[7] = f2h(b2.w);
        int byt = ((c & 127) << 4) ^ ((row & 7) << 4);
        *(short8*)(smw + (row << 10) + (byt >> 1)) = w.s;
    }
    // ============ init: logit fc rows [v0, v0+16) -> registers (A-fragments) ============
    const int v0 = wg * 16;
    const int vrowc = (v0 + ml < NV) ? v0 + ml : NV - 1;
    half8 la[16];
    #pragma unroll
    for (int j = 0; j < 16; ++j) {
        const float* src = fcw + (size_t)vrowc * NH + (kh << 9) + (j << 5) + kl8;
        union { unsigned short us[8]; short8 s; } w;
        #pragma unroll
        for (int e = 0; e < 8; ++e) w.us[e] = f2h(src[e]);
        la[j] = as_h8(w.s);
    }
    f32x4 fbv;
    #pragma unroll
    for (int r = 0; r < 4; ++r) {
        int v = v0 + rq + r;
        fbv[r] = fcb[v < NV ? v : NV - 1];
    }
    // pointwise roles
    const int b = tid & 63;       // batch
    const int q8 = tid >> 6;      // unit pair (0..7)
    float bs[4][2];
    #pragma unroll
    for (int q = 0; q < 4; ++q)
        #pragma unroll
        for (int j = 0; j < 2; ++j)
            bs[q][j] = Wb[(q << 10) + u0 + (q8 << 1) + j];
    float creg[2];                // cell state fp32, register-resident
    #pragma unroll
    for (int j = 0; j < 2; ++j)
        creg[j] = enc_c[(size_t)b * NH + u0 + (q8 << 1) + j];
    // blocked-ring read offset (within a 1024-short block): (b*16 + (kq&1)*8)
    const int rowoff = (((bt << 4) + ml) << 4) + ((kq & 1) << 3);
    __syncthreads();

    for (int p = 1; p <= TT + 1; ++p) {
        // embedding prefetch (plain cached loads; overlap the spin)
        unsigned int emb[4];
        if (p <= TT) {
            int idx = trg[b * TT + p - 1];
            #pragma unroll
            for (int q = 0; q < 4; ++q)
                emb[q] = *(const unsigned int*)(embT + (size_t)idx * 4096 + (q << 10) + u0 + (q8 << 1));
        }
        // wait: wave 0 only, packed-flag polls (coalesced sc1 loads, no RMW)
        if (tid < 64) {
            if (p > 1)
                while (__hip_atomic_load(gfl4 + tid, __ATOMIC_RELAXED, AGT) < p - 1) { }
            if (FCAD == 1 || (p & (FCAD - 1)) == 1)  // staleness-bounding acquire
                __builtin_amdgcn_fence(__ATOMIC_ACQUIRE, "agent");
        }
        __syncthreads();   // also drains last step's deferred out stores (free)

        const unsigned short* hh = hring + (size_t)((p - 1) & (RING - 1)) * 65536;
        // ONE shared h preload feeds both gate and logit MFMAs.
        // Blocked layout -> each wave reads contiguous 2KB regions.
        half8 hb[16];
        #pragma unroll
        for (int j = 0; j < 16; ++j) {
            int blk = (((kh << 4) + j) << 1) + (kq >> 1);
            hb[j] = as_h8(*(const short8*)(hh + (blk << 10) + rowoff));
        }

        // ---------------- gate phase (critical path) ----------------
        if (p <= TT) {
            f32x4 acc[4] = {};
            #pragma unroll
            for (int j = 0; j < 16; ++j) {
                int kb = (((kh << 4) + j) << 5) + kl8;
                #pragma unroll
                for (int rt = 0; rt < 4; ++rt) {
                    int row = (rt << 4) + ml;
                    int byt = (kb << 1) ^ ((row & 7) << 4);
                    half8 a = as_h8(*(const short8*)(smw + (row << 10) + (byt >> 1)));
                    acc[rt] = __builtin_amdgcn_mfma_f32_16x16x32_f16(a, hb[j], acc[rt], 0, 0, 0);
                }
            }
            if (kh) {
                #pragma unroll
                for (int rt = 0; rt < 4; ++rt)
                    #pragma unroll
                    for (int r = 0; r < 4; ++r)
                        gl[rt][rq + r][(bt << 4) + ml] = acc[rt][r];
            }
            __syncthreads();
            if (!kh) {
                #pragma unroll
                for (int rt = 0; rt < 4; ++rt)
                    #pragma unroll
                    for (int r = 0; r < 4; ++r)
                        gl[rt][rq + r][(bt << 4) + ml] += acc[rt][r];
            }
            __syncthreads();
            // pointwise: thread handles batch b, units q8*2..+1 -> LDS h tile
            unsigned int hw = 0;
            #pragma unroll
            for (int j = 0; j < 2; ++j) {
                int u = (q8 << 1) + j;
                float pi = gl[0][u][b] + bs[0][j] + bf2f((unsigned short)(emb[0] >> (j * 16)));
                float pf = gl[1][u][b] + bs[1][j] + bf2f((unsigned short)(emb[1] >> (j * 16)));
                float pg = gl[2][u][b] + bs[2][j] + bf2f((unsigned short)(emb[2] >> (j * 16)));
                float po = gl[3][u][b] + bs[3][j] + bf2f((unsigned short)(emb[3] >> (j * 16)));
                float ii = sigm(pi), ff = sigm(pf), gg = tanh_f(pg), oo = sigm(po);
                float cc = ff * creg[j] + ii * gg;
                creg[j] = cc;
                float hv = oo * tanh_f(cc);
                hw |= (unsigned int)f2h(hv) << (j * 16);
            }
            *(unsigned int*)&ht[b][q8 << 1] = hw;
            __syncthreads();
            // coalesced h publish: 128 threads x 16B contiguous into this WG's block
            if (tid < 128) {
                int b2 = tid >> 1, u8 = (tid & 1) << 3;
                const unsigned long long* hp = (const unsigned long long*)&ht[b2][u8];
                unsigned long long a0 = hp[0], a1 = hp[1];
                unsigned short* dst = hring + (size_t)(p & (RING - 1)) * 65536
                                      + (wg << 10) + (b2 << 4) + u8;
                __hip_atomic_store((unsigned long long*)dst, a0, __ATOMIC_RELAXED, AGT);
                __hip_atomic_store((unsigned long long*)(dst + 4), a1, __ATOMIC_RELAXED, AGT);
            }
            asm volatile("s_waitcnt vmcnt(0)" ::: "memory");  // h stores at coherence point
            __syncthreads();
            if (tid == 0)
                __hip_atomic_store(gfl4 + wg, p, __ATOMIC_RELAXED, AGT);  // RELEASE the step
        }

        // ---------------- logit phase for t = p-2 (off the critical path) ----------------
        if (p >= 2) {
            f32x4 accl = {};
            #pragma unroll
            for (int j = 0; j < 16; ++j)
                accl = __builtin_amdgcn_mfma_f32_16x16x32_f16(la[j], hb[j], accl, 0, 0, 0);
            if (kh) {
                #pragma unroll
                for (int r = 0; r < 4; ++r)
                    gl[0][rq + r][(bt << 4) + ml] = accl[r];
            }
            __syncthreads();
            if (!kh) {
                int bb = (bt << 4) + ml;
                f32x4 v = accl + fbv;
                #pragma unroll
                for (int r = 0; r < 4; ++r) v[r] += gl[0][rq + r][bb];
                #pragma unroll
                for (int r = 0; r < 4; ++r) ot[bb][rq + r] = v[r];
            }
            __syncthreads();
            // full-line out stores: 4 threads x 16B cover 64B of one row; aligned;
            // nontemporal (no-allocate, inv-safe); drain deferred to next spin.
            if (tid < 256) {
                int row = tid >> 2, seg = tid & 3;
                int vq = v0 + (seg << 2);
                f32x4 val;
                #pragma unroll
                for (int r = 0; r < 4; ++r) val[r] = ot[row][(seg << 2) + r];
                float* po = out + ((size_t)row * TT + (p - 2)) * NV + vq;
                if (vq + 3 < NV) {
                    __builtin_nontemporal_store(val, (f32x4*)po);
                } else {
                    #pragma unroll
                    for (int r = 0; r < 4; ++r)
                        if (vq + r < NV) __builtin_nontemporal_store(val[r], po + r);
                }
            }
            // no trailing barrier: post-spin barrier next iteration guards reuse
        }
    }
}

extern "C" void kernel_launch(void* const* d_in, const int* in_sizes, int n_in,
                              void* d_out, int out_size, void* d_ws, size_t ws_size,
                              hipStream_t stream) {
    const float* enc_h = (const float*)d_in[0];
    const float* enc_c = (const float*)d_in[1];
    const int* trg = (const int*)d_in[2];
    const float* Ww = (const float*)d_in[3];
    const float* Wb = (const float*)d_in[4];
    const float* fcw = (const float*)d_in[5];
    const float* fcb = (const float*)d_in[6];
    float* out = (float*)d_out;

    unsigned short* embT = (unsigned short*)d_ws;        // 1000 x 4096 bf16 (8 MB)
    unsigned short* hring = embT + (size_t)1000 * 4096;  // RING slots x 128 KB (fp16)

    const size_t embBytes = (size_t)1000 * 4096 * 2;
    const size_t slotBytes = (size_t)65536 * 2;
    const size_t need16 = embBytes + 16 * slotBytes + 8192;  // ~10.3 MB

    hipLaunchKernelGGL(embT_kernel, dim3(1024), dim3(256), 0, stream, Ww, embT);
    hipLaunchKernelGGL(h0_kernel, dim3(256), dim3(256), 0, stream, enc_h, hring);

    if (ws_size >= need16) {
        int* syn = (int*)(hring + (size_t)16 * 65536);
        hipMemsetAsync(syn, 0, 4096, stream);
        lstm_kernel<16, 8><<<dim3(NWG), dim3(512), 0, stream>>>(
            enc_c, trg, Ww, Wb, fcw, fcb, embT, hring, syn, out);
    } else {
        int* syn = (int*)(hring + (size_t)4 * 65536);
        hipMemsetAsync(syn, 0, 4096, stream);
        lstm_kernel<4, 1><<<dim3(NWG), dim3(512), 0, stream>>>(
            enc_c, trg, Ww, Wb, fcw, fcb, embT, hring, syn, out);
    }
}

// Round 12
// 1045.923 us; speedup vs baseline: 3.1287x; 1.4608x over previous
//
#include <hip/hip_runtime.h>

// Persistent LSTM decoder, FUSED gate+logit WGs, fp16 datapath, coalesced stores,
// TWO independent batch-groups (32 batches each, own ring+flags, no cross-coupling).
// 128 WGs x 256 thr (4 waves: b-tile 0..1 x k-half). Each WG owns 16 hidden units
// (gate weights LDS) and 16 vocab rows (fc weights in registers) for its group.
// h ring per group, per-WG BLOCKED [slot][wg 64][b 32][u 16] fp16: coalesced 16B
// sc1 publishes, contiguous consumer reads. Out: LDS-staged full-line nontemporal
// stores, drain deferred. Acquire fence BEFORE the spin (inv latency hides under
// the wait; staleness bound preserved: stale cachers happened-before the fence,
// post-spin reads are flag-ordered fresh). Packed 4B flags, no RMW anywhere.

#define TT 256
#define NH 1024
#define NV 1000
#define WROW 2024   // V + H
#define NGRP 2
#define GPW 64      // WGs per group
#define GB 32       // batches per group

typedef __attribute__((ext_vector_type(8))) short short8;
typedef __attribute__((ext_vector_type(8))) _Float16 half8;
typedef __attribute__((ext_vector_type(4))) float f32x4;

#define AGT __HIP_MEMORY_SCOPE_AGENT

__device__ __forceinline__ unsigned short f2bf(float f) {
    unsigned int u = __float_as_uint(f);
    u += 0x7fffu + ((u >> 16) & 1u);
    return (unsigned short)(u >> 16);
}
__device__ __forceinline__ float bf2f(unsigned short s) {
    return __uint_as_float(((unsigned int)s) << 16);
}
__device__ __forceinline__ unsigned short f2h(float f) {
    return __builtin_bit_cast(unsigned short, (_Float16)f);
}
__device__ __forceinline__ half8 as_h8(short8 s) {
    return __builtin_bit_cast(half8, s);
}
__device__ __forceinline__ float sigm(float x) {
    return __builtin_amdgcn_rcpf(1.0f + __expf(-x));
}
__device__ __forceinline__ float tanh_f(float x) {
    return 2.0f * __builtin_amdgcn_rcpf(1.0f + __expf(-2.0f * x)) - 1.0f;
}

// ---- one-time: transpose-cast embedding block Ww[:, :V] -> embT[V][4096] bf16
__global__ void embT_kernel(const float* __restrict__ Ww, unsigned short* __restrict__ embT) {
    __shared__ unsigned short tile[64][80];
    const int rt = blockIdx.x & 63, vt = blockIdx.x >> 6;
    const int r0 = rt * 64, v0 = vt * 64;
    const int t = threadIdx.x;
    {
        int rr = t >> 2, c0 = (t & 3) * 16;
        for (int j = 0; j < 16; ++j) {
            int v = v0 + c0 + j;
            float x = (v < NV) ? Ww[(size_t)(r0 + rr) * WROW + v] : 0.f;
            tile[c0 + j][rr] = f2bf(x);
        }
    }
    __syncthreads();
    {
        int vv = t >> 2, k0 = (t & 3) * 16;
        int v = v0 + vv;
        if (v < NV)
            for (int j = 0; j < 16; ++j)
                embT[(size_t)v * 4096 + r0 + k0 + j] = tile[vv][k0 + j];
    }
}

// ---- one-time: enc_h -> blocked fp16 slot 0 of each group's ring
__global__ void h0_kernel(const float* __restrict__ enc_h, unsigned short* __restrict__ hring,
                          int ring) {
    int i = blockIdx.x * 256 + threadIdx.x;  // 0..65535 over [64 b][1024 u]
    int b = i >> 10, u = i & 1023;
    int g = b >> 5, bl = b & 31;
    hring[(size_t)g * ring * 32768 + ((u >> 4) << 9) + (bl << 4) + (u & 15)] = f2h(enc_h[i]);
}

template <int RING, int FCAD>
__global__ void __launch_bounds__(256, 1)
lstm_kernel(const float* __restrict__ enc_c,
            const int* __restrict__ trg,
            const float* __restrict__ Ww,
            const float* __restrict__ Wb,
            const float* __restrict__ fcw,
            const float* __restrict__ fcb,
            const unsigned short* __restrict__ embT,
            unsigned short* __restrict__ hring,
            int* __restrict__ syn,
            float* __restrict__ out) {
    __shared__ unsigned short smw[65536];   // 128 KB: fp16 gate weights, XOR-swizzled
    __shared__ float gl[4][16][34];         // pre-acts [rowtile][row][col 0..31] (+pad)
    __shared__ unsigned short ht[32][20];   // h staging tile [b][u] (+pad)
    __shared__ float ot[32][17];            // logit staging tile [b][v-col] (+pad)

    const int wg = blockIdx.x;
    const int g = wg >> 6;        // batch-group
    const int iw = wg & 63;       // WG within group
    const int tid = threadIdx.x;
    const int wv = tid >> 6;      // 0..3
    const int lane = tid & 63;
    const int bt = wv >> 1;       // b-tile 0..1 (batch rows bt*16..+15, group-local)
    const int kh = wv & 1;        // k-half (kt 0..15 / 16..31)
    const int ml = lane & 15;
    const int kq = lane >> 4;
    const int kl8 = kq * 8;
    const int rq = kq * 4;
    const int gB = g * GB;
    int* gfl4 = syn + g * 64;     // this group's 64 epoch flags, packed 4B
    unsigned short* hbase = hring + (size_t)g * RING * 32768;

    // ============ init: gate weights -> LDS ============
    const int u0 = iw * 16;       // hidden units [u0, u0+16)
    for (int c = tid; c < 8192; c += 256) {   // 64 rows x 1024 fp16 -> LDS
        int row = c >> 7;
        int col8 = (c & 127) << 3;
        int grow = ((row >> 4) << 10) + u0 + (row & 15);   // q*1024 + u0 + uu
        const float* src = Ww + (size_t)grow * WROW + 1000 + col8;
        float4 a = *(const float4*)src;
        float4 b2 = *(const float4*)(src + 4);
        union { unsigned short us[8]; short8 s; } w;
        w.us[0] = f2h(a.x); w.us[1] = f2h(a.y); w.us[2] = f2h(a.z); w.us[3] = f2h(a.w);
        w.us[4] = f2h(b2.x); w.us[5] = f2h(b2.y); w.us[6] = f2h(b2.z); w.us[7] = f2h(b2.w);
        int byt = ((c & 127) << 4) ^ ((row & 7) << 4);
        *(short8*)(smw + (row << 10) + (byt >> 1)) = w.s;
    }
    // ============ init: logit fc rows [v0, v0+16) -> registers (A-fragments) ============
    const int v0 = iw * 16;
    const int vrowc = (v0 + ml < NV) ? v0 + ml : NV - 1;
    half8 la[16];
    #pragma unroll
    for (int j = 0; j < 16; ++j) {
        const float* src = fcw + (size_t)vrowc * NH + (kh << 9) + (j << 5) + kl8;
        union { unsigned short us[8]; short8 s; } w;
        #pragma unroll
        for (int e = 0; e < 8; ++e) w.us[e] = f2h(src[e]);
        la[j] = as_h8(w.s);
    }
    f32x4 fbv;
    #pragma unroll
    for (int r = 0; r < 4; ++r) {
        int v = v0 + rq + r;
        fbv[r] = fcb[v < NV ? v : NV - 1];
    }
    // pointwise roles: thread -> (group-local batch b, unit pair q8)
    const int b = tid & 31;
    const int q8 = tid >> 5;      // 0..7
    float bs[4][2];
    #pragma unroll
    for (int q = 0; q < 4; ++q)
        #pragma unroll
        for (int j = 0; j < 2; ++j)
            bs[q][j] = Wb[(q << 10) + u0 + (q8 << 1) + j];
    float creg[2];                // cell state fp32, register-resident
    #pragma unroll
    for (int j = 0; j < 2; ++j)
        creg[j] = enc_c[(size_t)(gB + b) * NH + u0 + (q8 << 1) + j];
    // blocked-ring read offset within a 512-short block: b-row*16 + 8*(kq&1)
    const int rowoff = (((bt << 4) + ml) << 4) + ((kq & 1) << 3);
    __syncthreads();

    for (int p = 1; p <= TT + 1; ++p) {
        // embedding prefetch (plain cached loads; overlap the spin)
        unsigned int emb[4];
        if (p <= TT) {
            int idx = trg[(gB + b) * TT + p - 1];
            #pragma unroll
            for (int q = 0; q < 4; ++q)
                emb[q] = *(const unsigned int*)(embT + (size_t)idx * 4096 + (q << 10) + u0 + (q8 << 1));
        }
        // wave 0: fence FIRST (inv hides under the spin), then packed-flag polls
        if (tid < 64) {
            if (FCAD == 1 || (p & (FCAD - 1)) == 1)
                __builtin_amdgcn_fence(__ATOMIC_ACQUIRE, "agent");
            if (p > 1)
                while (__hip_atomic_load(gfl4 + tid, __ATOMIC_RELAXED, AGT) < p - 1) { }
        }
        __syncthreads();   // also drains last step's deferred out stores (free)

        const unsigned short* hh = hbase + (size_t)((p - 1) & (RING - 1)) * 32768;
        // ONE shared h preload feeds both gate and logit MFMAs (contiguous blocks)
        half8 hb[16];
        #pragma unroll
        for (int j = 0; j < 16; ++j) {
            int blk = (((kh << 4) + j) << 1) + (kq >> 1);
            hb[j] = as_h8(*(const short8*)(hh + (blk << 9) + rowoff));
        }

        // ---------------- gate phase (critical path) ----------------
        if (p <= TT) {
            f32x4 acc[4] = {};
            #pragma unroll
            for (int j = 0; j < 16; ++j) {
                int kb = (((kh << 4) + j) << 5) + kl8;
                #pragma unroll
                for (int rt = 0; rt < 4; ++rt) {
                    int row = (rt << 4) + ml;
                    int byt = (kb << 1) ^ ((row & 7) << 4);
                    half8 a = as_h8(*(const short8*)(smw + (row << 10) + (byt >> 1)));
                    acc[rt] = __builtin_amdgcn_mfma_f32_16x16x32_f16(a, hb[j], acc[rt], 0, 0, 0);
                }
            }
            if (kh) {
                #pragma unroll
                for (int rt = 0; rt < 4; ++rt)
                    #pragma unroll
                    for (int r = 0; r < 4; ++r)
                        gl[rt][rq + r][(bt << 4) + ml] = acc[rt][r];
            }
            __syncthreads();
            if (!kh) {
                #pragma unroll
                for (int rt = 0; rt < 4; ++rt)
                    #pragma unroll
                    for (int r = 0; r < 4; ++r)
                        gl[rt][rq + r][(bt << 4) + ml] += acc[rt][r];
            }
            __syncthreads();
            // pointwise: thread handles group-local batch b, units q8*2..+1
            unsigned int hw = 0;
            #pragma unroll
            for (int j = 0; j < 2; ++j) {
                int u = (q8 << 1) + j;
                float pi = gl[0][u][b] + bs[0][j] + bf2f((unsigned short)(emb[0] >> (j * 16)));
                float pf = gl[1][u][b] + bs[1][j] + bf2f((unsigned short)(emb[1] >> (j * 16)));
                float pg = gl[2][u][b] + bs[2][j] + bf2f((unsigned short)(emb[2] >> (j * 16)));
                float po = gl[3][u][b] + bs[3][j] + bf2f((unsigned short)(emb[3] >> (j * 16)));
                float ii = sigm(pi), ff = sigm(pf), gg = tanh_f(pg), oo = sigm(po);
                float cc = ff * creg[j] + ii * gg;
                creg[j] = cc;
                float hv = oo * tanh_f(cc);
                hw |= (unsigned int)f2h(hv) << (j * 16);
            }
            *(unsigned int*)&ht[b][q8 << 1] = hw;
            __syncthreads();
            // coalesced h publish: 64 threads x 16B contiguous into this WG's block
            if (tid < 64) {
                int b2 = tid >> 1, u8 = (tid & 1) << 3;
                const unsigned long long* hp = (const unsigned long long*)&ht[b2][u8];
                unsigned long long a0 = hp[0], a1 = hp[1];
                unsigned short* dst = hbase + (size_t)(p & (RING - 1)) * 32768
                                      + (iw << 9) + (b2 << 4) + u8;
                __hip_atomic_store((unsigned long long*)dst, a0, __ATOMIC_RELAXED, AGT);
                __hip_atomic_store((unsigned long long*)(dst + 4), a1, __ATOMIC_RELAXED, AGT);
            }
            asm volatile("s_waitcnt vmcnt(0)" ::: "memory");  // h stores at coherence point
            __syncthreads();
            if (tid == 0)
                __hip_atomic_store(gfl4 + iw, p, __ATOMIC_RELAXED, AGT);  // RELEASE the step
        }

        // ---------------- logit phase for t = p-2 (uses hb = h_{p-1}) ----------------
        if (p >= 2) {
            f32x4 accl = {};
            #pragma unroll
            for (int j = 0; j < 16; ++j)
                accl = __builtin_amdgcn_mfma_f32_16x16x32_f16(la[j], hb[j], accl, 0, 0, 0);
            if (kh) {
                #pragma unroll
                for (int r = 0; r < 4; ++r)
                    gl[0][rq + r][(bt << 4) + ml] = accl[r];
            }
            __syncthreads();
            if (!kh) {
                int bb = (bt << 4) + ml;
                f32x4 v = accl + fbv;
                #pragma unroll
                for (int r = 0; r < 4; ++r) v[r] += gl[0][rq + r][bb];
                #pragma unroll
                for (int r = 0; r < 4; ++r) ot[bb][rq + r] = v[r];
            }
            __syncthreads();
            // full-line out stores: 4 threads x 16B cover 64B of one row; aligned
            // (row stride 4000 B = 250 x 16); nontemporal; drain deferred to next spin.
            if (tid < 128) {
                int row = tid >> 2, seg = tid & 3;
                int vq = v0 + (seg << 2);
                f32x4 val;
                #pragma unroll
                for (int r = 0; r < 4; ++r) val[r] = ot[row][(seg << 2) + r];
                float* po = out + ((size_t)(gB + row) * TT + (p - 2)) * NV + vq;
                if (vq + 3 < NV) {
                    __builtin_nontemporal_store(val, (f32x4*)po);
                } else {
                    #pragma unroll
                    for (int r = 0; r < 4; ++r)
                        if (vq + r < NV) __builtin_nontemporal_store(val[r], po + r);
                }
            }
            // no trailing barrier: post-spin barrier next iteration guards LDS reuse
        }
    }
}

extern "C" void kernel_launch(void* const* d_in, const int* in_sizes, int n_in,
                              void* d_out, int out_size, void* d_ws, size_t ws_size,
                              hipStream_t stream) {
    const float* enc_h = (const float*)d_in[0];
    const float* enc_c = (const float*)d_in[1];
    const int* trg = (const int*)d_in[2];
    const float* Ww = (const float*)d_in[3];
    const float* Wb = (const float*)d_in[4];
    const float* fcw = (const float*)d_in[5];
    const float* fcb = (const float*)d_in[6];
    float* out = (float*)d_out;

    unsigned short* embT = (unsigned short*)d_ws;        // 1000 x 4096 bf16 (8 MB)
    unsigned short* hring = embT + (size_t)1000 * 4096;  // [2 grp][RING][32768] fp16

    const size_t embBytes = (size_t)1000 * 4096 * 2;
    const size_t slotBytes = (size_t)32768 * 2;
    const size_t need16 = embBytes + (size_t)NGRP * 16 * slotBytes + 8192;  // ~10.1 MB

    hipLaunchKernelGGL(embT_kernel, dim3(1024), dim3(256), 0, stream, Ww, embT);

    if (ws_size >= need16) {
        int* syn = (int*)(hring + (size_t)NGRP * 16 * 32768);
        hipMemsetAsync(syn, 0, 4096, stream);
        hipLaunchKernelGGL(h0_kernel, dim3(256), dim3(256), 0, stream, enc_h, hring, 16);
        lstm_kernel<16, 8><<<dim3(NGRP * GPW), dim3(256), 0, stream>>>(
            enc_c, trg, Ww, Wb, fcw, fcb, embT, hring, syn, out);
    } else {
        int* syn = (int*)(hring + (size_t)NGRP * 4 * 32768);
        hipMemsetAsync(syn, 0, 4096, stream);
        hipLaunchKernelGGL(h0_kernel, dim3(256), dim3(256), 0, stream, enc_h, hring, 4);
        lstm_kernel<4, 1><<<dim3(NGRP * GPW), dim3(256), 0, stream>>>(
            enc_c, trg, Ww, Wb, fcw, fcb, embT, hring, syn, out);
    }
}

// Round 13
// 867.997 us; speedup vs baseline: 3.7700x; 1.2050x over previous
//
#include <hip/hip_runtime.h>

// Persistent LSTM decoder, FUSED gate+logit WGs, fp16 datapath, coalesced stores,
// FOUR independent batch-groups (16 batches each, own ring+flags).
// 256 WGs x 256 thr (4 waves = k-quarters). Each WG owns 16 hidden units (gate
// weights LDS, XOR-swizzled) and 16 vocab rows (fc weights in registers) for its
// group. Partial K-sums combined via 4 gl planes summed at the consumer threads.
// h ring per group, per-WG BLOCKED [slot][wg 64][b 16][u 16] fp16: 16B coalesced
// sc1 publishes, contiguous reads. Out: full-line nontemporal stores straight
// from gl planes, drain deferred under next spin. Acquire fence BEFORE the spin.
// Packed 4B flags, no RMW. Protocol identical to r12 (proven).

#define TT 256
#define NH 1024
#define NV 1000
#define WROW 2024   // V + H
#define NGRP 4
#define GPW 64      // WGs per group
#define GB 16       // batches per group

typedef __attribute__((ext_vector_type(8))) short short8;
typedef __attribute__((ext_vector_type(8))) _Float16 half8;
typedef __attribute__((ext_vector_type(4))) float f32x4;

#define AGT __HIP_MEMORY_SCOPE_AGENT

__device__ __forceinline__ unsigned short f2bf(float f) {
    unsigned int u = __float_as_uint(f);
    u += 0x7fffu + ((u >> 16) & 1u);
    return (unsigned short)(u >> 16);
}
__device__ __forceinline__ float bf2f(unsigned short s) {
    return __uint_as_float(((unsigned int)s) << 16);
}
__device__ __forceinline__ unsigned short f2h(float f) {
    return __builtin_bit_cast(unsigned short, (_Float16)f);
}
__device__ __forceinline__ half8 as_h8(short8 s) {
    return __builtin_bit_cast(half8, s);
}
__device__ __forceinline__ float sigm(float x) {
    return __builtin_amdgcn_rcpf(1.0f + __expf(-x));
}
__device__ __forceinline__ float tanh_f(float x) {
    return 2.0f * __builtin_amdgcn_rcpf(1.0f + __expf(-2.0f * x)) - 1.0f;
}

// ---- one-time: transpose-cast embedding block Ww[:, :V] -> embT[V][4096] bf16
__global__ void embT_kernel(const float* __restrict__ Ww, unsigned short* __restrict__ embT) {
    __shared__ unsigned short tile[64][80];
    const int rt = blockIdx.x & 63, vt = blockIdx.x >> 6;
    const int r0 = rt * 64, v0 = vt * 64;
    const int t = threadIdx.x;
    {
        int rr = t >> 2, c0 = (t & 3) * 16;
        for (int j = 0; j < 16; ++j) {
            int v = v0 + c0 + j;
            float x = (v < NV) ? Ww[(size_t)(r0 + rr) * WROW + v] : 0.f;
            tile[c0 + j][rr] = f2bf(x);
        }
    }
    __syncthreads();
    {
        int vv = t >> 2, k0 = (t & 3) * 16;
        int v = v0 + vv;
        if (v < NV)
            for (int j = 0; j < 16; ++j)
                embT[(size_t)v * 4096 + r0 + k0 + j] = tile[vv][k0 + j];
    }
}

// ---- one-time: enc_h -> blocked fp16 slot 0 of each group's ring
__global__ void h0_kernel(const float* __restrict__ enc_h, unsigned short* __restrict__ hring,
                          int ring) {
    int i = blockIdx.x * 256 + threadIdx.x;  // 0..65535 over [64 b][1024 u]
    int b = i >> 10, u = i & 1023;
    int g = b >> 4, bl = b & 15;
    hring[(size_t)g * ring * 16384 + ((u >> 4) << 8) + (bl << 4) + (u & 15)] = f2h(enc_h[i]);
}

template <int RING, int FCAD>
__global__ void __launch_bounds__(256, 1)
lstm_kernel(const float* __restrict__ enc_c,
            const int* __restrict__ trg,
            const float* __restrict__ Ww,
            const float* __restrict__ Wb,
            const float* __restrict__ fcw,
            const float* __restrict__ fcb,
            const unsigned short* __restrict__ embT,
            unsigned short* __restrict__ hring,
            int* __restrict__ syn,
            float* __restrict__ out) {
    __shared__ unsigned short smw[65536];   // 128 KB: fp16 gate weights, XOR-swizzled
    __shared__ float gl[4][4][16][18];      // partial planes [kq4][rt][row][col(+pad)]
    __shared__ unsigned short ht[16][20];   // h staging tile [b][u] (+pad)

    const int wg = blockIdx.x;
    const int g = wg >> 6;        // batch-group
    const int iw = wg & 63;       // WG within group
    const int tid = threadIdx.x;
    const int wv = tid >> 6;      // 0..3 = k-quarter (K range wv*256..+255)
    const int lane = tid & 63;
    const int ml = lane & 15;
    const int kq = lane >> 4;
    const int kl8 = kq * 8;
    const int rq = kq * 4;
    const int gB = g * GB;
    int* gfl4 = syn + g * 64;     // this group's 64 epoch flags, packed 4B
    unsigned short* hbase = hring + (size_t)g * RING * 16384;

    // ============ init: gate weights -> LDS ============
    const int u0 = iw * 16;       // hidden units [u0, u0+16)
    for (int c = tid; c < 8192; c += 256) {   // 64 rows x 1024 fp16 -> LDS
        int row = c >> 7;
        int col8 = (c & 127) << 3;
        int grow = ((row >> 4) << 10) + u0 + (row & 15);   // q*1024 + u0 + uu
        const float* src = Ww + (size_t)grow * WROW + 1000 + col8;
        float4 a = *(const float4*)src;
        float4 b2 = *(const float4*)(src + 4);
        union { unsigned short us[8]; short8 s; } w;
        w.us[0] = f2h(a.x); w.us[1] = f2h(a.y); w.us[2] = f2h(a.z); w.us[3] = f2h(a.w);
        w.us[4] = f2h(b2.x); w.us[5] = f2h(b2.y); w.us[6] = f2h(b2.z); w.us[7] = f2h(b2.w);
        int byt = ((c & 127) << 4) ^ ((row & 7) << 4);
        *(short8*)(smw + (row << 10) + (byt >> 1)) = w.s;
    }
    // ============ init: logit fc rows [v0, v0+16) -> registers (A-fragments) ============
    const int v0 = iw * 16;
    const int vrowc = (v0 + ml < NV) ? v0 + ml : NV - 1;
    half8 la[8];
    #pragma unroll
    for (int j = 0; j < 8; ++j) {
        const float* src = fcw + (size_t)vrowc * NH + (((wv << 3) + j) << 5) + kl8;
        union { unsigned short us[8]; short8 s; } w;
        #pragma unroll
        for (int e = 0; e < 8; ++e) w.us[e] = f2h(src[e]);
        la[j] = as_h8(w.s);
    }
    // pointwise roles: thread -> (group-local batch b, unit u)
    const int b = tid & 15;
    const int u = tid >> 4;       // 0..15
    float bs[4];
    #pragma unroll
    for (int q = 0; q < 4; ++q)
        bs[q] = Wb[(q << 10) + u0 + u];
    float creg = enc_c[(size_t)(gB + b) * NH + u0 + u];
    // store roles (tid<64): srow = batch, sseg = 4-float segment of the 16-v tile
    const int srow = tid >> 2, sseg = tid & 3;
    float fbs[4];
    #pragma unroll
    for (int r = 0; r < 4; ++r) {
        int v = v0 + (sseg << 2) + r;
        fbs[r] = fcb[v < NV ? v : NV - 1];
    }
    __syncthreads();

    for (int p = 1; p <= TT + 1; ++p) {
        // embedding prefetch (plain cached loads; overlap the spin)
        unsigned short emb[4];
        if (p <= TT) {
            int idx = trg[(gB + b) * TT + p - 1];
            #pragma unroll
            for (int q = 0; q < 4; ++q)
                emb[q] = embT[(size_t)idx * 4096 + (q << 10) + u0 + u];
        }
        // wave 0: fence FIRST (inv hides under the spin), then packed-flag polls
        if (tid < 64) {
            if (FCAD == 1 || (p & (FCAD - 1)) == 1)
                __builtin_amdgcn_fence(__ATOMIC_ACQUIRE, "agent");
            if (p > 1)
                while (__hip_atomic_load(gfl4 + tid, __ATOMIC_RELAXED, AGT) < p - 1) { }
        }
        __syncthreads();   // B1: also drains last step's deferred out stores

        const unsigned short* hh = hbase + (size_t)((p - 1) & (RING - 1)) * 16384;
        // this wave's 8 h fragments (K range wv*256..+255), contiguous blocked reads
        half8 hb[8];
        #pragma unroll
        for (int j = 0; j < 8; ++j) {
            int wgp = (wv << 4) + (j << 1) + (kq >> 1);
            hb[j] = as_h8(*(const short8*)(hh + (wgp << 8) + (ml << 4) + ((kq & 1) << 3)));
        }

        // ---------------- gate phase (critical path) ----------------
        if (p <= TT) {
            f32x4 acc[4] = {};
            #pragma unroll
            for (int j = 0; j < 8; ++j) {
                int kb = (((wv << 3) + j) << 5) + kl8;
                #pragma unroll
                for (int rt = 0; rt < 4; ++rt) {
                    int row = (rt << 4) + ml;
                    int byt = (kb << 1) ^ ((row & 7) << 4);
                    half8 a = as_h8(*(const short8*)(smw + (row << 10) + (byt >> 1)));
                    acc[rt] = __builtin_amdgcn_mfma_f32_16x16x32_f16(a, hb[j], acc[rt], 0, 0, 0);
                }
            }
            #pragma unroll
            for (int rt = 0; rt < 4; ++rt)
                #pragma unroll
                for (int r = 0; r < 4; ++r)
                    gl[wv][rt][rq + r][ml] = acc[rt][r];
            __syncthreads();   // B2
            // pointwise: thread (b, u) sums the 4 K-planes per gate
            float pre[4];
            #pragma unroll
            for (int q = 0; q < 4; ++q)
                pre[q] = gl[0][q][u][b] + gl[1][q][u][b] + gl[2][q][u][b] + gl[3][q][u][b]
                         + bs[q] + bf2f(emb[q]);
            float ii = sigm(pre[0]), ff = sigm(pre[1]);
            float gg = tanh_f(pre[2]), oo = sigm(pre[3]);
            float cc = ff * creg + ii * gg;
            creg = cc;
            ht[b][u] = f2h(oo * tanh_f(cc));
            __syncthreads();   // B3
            // coalesced h publish: 32 threads x 16B contiguous into this WG's block
            if (tid < 32) {
                int b2 = tid >> 1, u8 = (tid & 1) << 3;
                unsigned long long a0 = *(const unsigned long long*)&ht[b2][u8];
                a0 |= (unsigned long long)(*(const unsigned int*)&ht[b2][u8 + 4]) << 32;
                // (ht row is 20 shorts; [u8..u8+7] spans 16B but may straddle the
                //  8B boundary -- assemble from 8B+4B+4B to stay in-bounds)
                unsigned long long lo = *(const unsigned long long*)&ht[b2][u8];
                unsigned long long hi;
                memcpy(&hi, &ht[b2][u8 + 4], 8);
                unsigned short* dst = hbase + (size_t)(p & (RING - 1)) * 16384
                                      + (iw << 8) + (b2 << 4) + u8;
                __hip_atomic_store((unsigned long long*)dst, lo, __ATOMIC_RELAXED, AGT);
                __hip_atomic_store((unsigned long long*)(dst + 4), hi, __ATOMIC_RELAXED, AGT);
            }
            asm volatile("s_waitcnt vmcnt(0)" ::: "memory");  // h stores at coherence point
            __syncthreads();   // B4
            if (tid == 0)
                __hip_atomic_store(gfl4 + iw, p, __ATOMIC_RELAXED, AGT);  // RELEASE
        }

        // ---------------- logit phase for t = p-2 (uses hb = h_{p-1}) ----------------
        if (p >= 2) {
            f32x4 accl = {};
            #pragma unroll
            for (int j = 0; j < 8; ++j)
                accl = __builtin_amdgcn_mfma_f32_16x16x32_f16(la[j], hb[j], accl, 0, 0, 0);
            #pragma unroll
            for (int r = 0; r < 4; ++r)
                gl[wv][0][rq + r][ml] = accl[r];
            __syncthreads();   // B5
            // fused finalize + full-line stores: 4 threads x 16B cover 64B of a row
            if (tid < 64) {
                int vq = v0 + (sseg << 2);
                f32x4 val;
                #pragma unroll
                for (int r = 0; r < 4; ++r) {
                    int rowi = (sseg << 2) + r;
                    val[r] = gl[0][0][rowi][srow] + gl[1][0][rowi][srow]
                           + gl[2][0][rowi][srow] + gl[3][0][rowi][srow] + fbs[r];
                }
                float* po = out + ((size_t)(gB + srow) * TT + (p - 2)) * NV + vq;
                if (vq + 3 < NV) {
                    __builtin_nontemporal_store(val, (f32x4*)po);
                } else {
                    #pragma unroll
                    for (int r = 0; r < 4; ++r)
                        if (vq + r < NV) __builtin_nontemporal_store(val[r], po + r);
                }
            }
            // no trailing barrier: next iteration's B1 guards gl reuse
        }
    }
}

extern "C" void kernel_launch(void* const* d_in, const int* in_sizes, int n_in,
                              void* d_out, int out_size, void* d_ws, size_t ws_size,
                              hipStream_t stream) {
    const float* enc_h = (const float*)d_in[0];
    const float* enc_c = (const float*)d_in[1];
    const int* trg = (const int*)d_in[2];
    const float* Ww = (const float*)d_in[3];
    const float* Wb = (const float*)d_in[4];
    const float* fcw = (const float*)d_in[5];
    const float* fcb = (const float*)d_in[6];
    float* out = (float*)d_out;

    unsigned short* embT = (unsigned short*)d_ws;        // 1000 x 4096 bf16 (8 MB)
    unsigned short* hring = embT + (size_t)1000 * 4096;  // [4 grp][RING][16384] fp16

    const size_t embBytes = (size_t)1000 * 4096 * 2;
    const size_t slotBytes = (size_t)16384 * 2;
    const size_t need16 = embBytes + (size_t)NGRP * 16 * slotBytes + 8192;  // ~10.5 MB

    hipLaunchKernelGGL(embT_kernel, dim3(1024), dim3(256), 0, stream, Ww, embT);

    if (ws_size >= need16) {
        int* syn = (int*)(hring + (size_t)NGRP * 16 * 16384);
        hipMemsetAsync(syn, 0, 4096, stream);
        hipLaunchKernelGGL(h0_kernel, dim3(256), dim3(256), 0, stream, enc_h, hring, 16);
        lstm_kernel<16, 8><<<dim3(NGRP * GPW), dim3(256), 0, stream>>>(
            enc_c, trg, Ww, Wb, fcw, fcb, embT, hring, syn, out);
    } else {
        int* syn = (int*)(hring + (size_t)NGRP * 4 * 16384);
        hipMemsetAsync(syn, 0, 4096, stream);
        hipLaunchKernelGGL(h0_kernel, dim3(256), dim3(256), 0, stream, enc_h, hring, 4);
        lstm_kernel<4, 1><<<dim3(NGRP * GPW), dim3(256), 0, stream>>>(
            enc_c, trg, Ww, Wb, fcw, fcb, embT, hring, syn, out);
    }
}

// Round 14
// 840.093 us; speedup vs baseline: 3.8952x; 1.0332x over previous
//
#include <hip/hip_runtime.h>

// Persistent LSTM decoder, FUSED gate+logit WGs, fp16 datapath, coalesced stores,
// FOUR independent batch-groups (16 batches each, own ring+flags).
// 256 WGs x 256 thr (4 waves = k-quarters). XCD-swizzled: each group's 64 WGs
// sit on exactly 2 XCDs (h broadcast becomes L2-local, L3 fills x8 -> x2).
// Each WG owns 16 hidden units (gate weights LDS, XOR-swizzled) and 16 vocab
// rows (fc weights in registers). Partial K-sums via 4 gl planes.
// Critical path slimmed: h publish + vmcnt drain + flag release all in wave 0
// (per-wave vmcnt => NO barrier before release); waves 1-3 run logit MFMAs
// during the drain; logit finalize/stores on wave 1 (wave 0 never drains them).
// Acquire fence BEFORE the spin. Packed 4B flags, no RMW anywhere.

#define TT 256
#define NH 1024
#define NV 1000
#define WROW 2024   // V + H
#define NGRP 4
#define GPW 64      // WGs per group
#define GB 16       // batches per group

typedef __attribute__((ext_vector_type(8))) short short8;
typedef __attribute__((ext_vector_type(8))) _Float16 half8;
typedef __attribute__((ext_vector_type(4))) float f32x4;

#define AGT __HIP_MEMORY_SCOPE_AGENT

__device__ __forceinline__ unsigned short f2bf(float f) {
    unsigned int u = __float_as_uint(f);
    u += 0x7fffu + ((u >> 16) & 1u);
    return (unsigned short)(u >> 16);
}
__device__ __forceinline__ float bf2f(unsigned short s) {
    return __uint_as_float(((unsigned int)s) << 16);
}
__device__ __forceinline__ unsigned short f2h(float f) {
    return __builtin_bit_cast(unsigned short, (_Float16)f);
}
__device__ __forceinline__ half8 as_h8(short8 s) {
    return __builtin_bit_cast(half8, s);
}
__device__ __forceinline__ float sigm(float x) {
    return __builtin_amdgcn_rcpf(1.0f + __expf(-x));
}
__device__ __forceinline__ float tanh_f(float x) {
    return 2.0f * __builtin_amdgcn_rcpf(1.0f + __expf(-2.0f * x)) - 1.0f;
}

// ---- one-time: transpose-cast embedding block Ww[:, :V] -> embT[V][4096] bf16
__global__ void embT_kernel(const float* __restrict__ Ww, unsigned short* __restrict__ embT) {
    __shared__ unsigned short tile[64][80];
    const int rt = blockIdx.x & 63, vt = blockIdx.x >> 6;
    const int r0 = rt * 64, v0 = vt * 64;
    const int t = threadIdx.x;
    {
        int rr = t >> 2, c0 = (t & 3) * 16;
        for (int j = 0; j < 16; ++j) {
            int v = v0 + c0 + j;
            float x = (v < NV) ? Ww[(size_t)(r0 + rr) * WROW + v] : 0.f;
            tile[c0 + j][rr] = f2bf(x);
        }
    }
    __syncthreads();
    {
        int vv = t >> 2, k0 = (t & 3) * 16;
        int v = v0 + vv;
        if (v < NV)
            for (int j = 0; j < 16; ++j)
                embT[(size_t)v * 4096 + r0 + k0 + j] = tile[vv][k0 + j];
    }
}

// ---- one-time: enc_h -> blocked fp16 slot 0 of each group's ring
__global__ void h0_kernel(const float* __restrict__ enc_h, unsigned short* __restrict__ hring,
                          int ring) {
    int i = blockIdx.x * 256 + threadIdx.x;  // 0..65535 over [64 b][1024 u]
    int b = i >> 10, u = i & 1023;
    int g = b >> 4, bl = b & 15;
    hring[(size_t)g * ring * 16384 + ((u >> 4) << 8) + (bl << 4) + (u & 15)] = f2h(enc_h[i]);
}

template <int RING, int FCAD>
__global__ void __launch_bounds__(256, 1)
lstm_kernel(const float* __restrict__ enc_c,
            const int* __restrict__ trg,
            const float* __restrict__ Ww,
            const float* __restrict__ Wb,
            const float* __restrict__ fcw,
            const float* __restrict__ fcb,
            const unsigned short* __restrict__ embT,
            unsigned short* __restrict__ hring,
            int* __restrict__ syn,
            float* __restrict__ out) {
    __shared__ unsigned short smw[65536];   // 128 KB: fp16 gate weights, XOR-swizzled
    __shared__ float gl[4][4][16][18];      // partial planes [kq4][rt][row][col(+pad)]
    __shared__ unsigned short ht[16][20];   // h staging tile [b][u] (+pad)

    // XCD swizzle: physical block -> (group, iw) s.t. group g occupies XCDs {2g,2g+1}
    // (dispatch round-robins blocks over 8 XCDs: xcd = blockIdx % 8)
    const int pb = blockIdx.x;
    const int xcd = pb & 7;
    const int g = xcd >> 1;                 // batch-group
    const int iw = ((xcd & 1) << 5) + (pb >> 3);  // WG within group, 0..63
    const int tid = threadIdx.x;
    const int wv = tid >> 6;      // 0..3 = k-quarter (K range wv*256..+255)
    const int lane = tid & 63;
    const int ml = lane & 15;
    const int kq = lane >> 4;
    const int kl8 = kq * 8;
    const int rq = kq * 4;
    const int gB = g * GB;
    int* gfl4 = syn + g * 64;     // this group's 64 epoch flags, packed 4B
    unsigned short* hbase = hring + (size_t)g * RING * 16384;

    // ============ init: gate weights -> LDS ============
    const int u0 = iw * 16;       // hidden units [u0, u0+16)
    for (int c = tid; c < 8192; c += 256) {   // 64 rows x 1024 fp16 -> LDS
        int row = c >> 7;
        int col8 = (c & 127) << 3;
        int grow = ((row >> 4) << 10) + u0 + (row & 15);   // q*1024 + u0 + uu
        const float* src = Ww + (size_t)grow * WROW + 1000 + col8;
        float4 a = *(const float4*)src;
        float4 b2 = *(const float4*)(src + 4);
        union { unsigned short us[8]; short8 s; } w;
        w.us[0] = f2h(a.x); w.us[1] = f2h(a.y); w.us[2] = f2h(a.z); w.us[3] = f2h(a.w);
        w.us[4] = f2h(b2.x); w.us[5] = f2h(b2.y); w.us[6] = f2h(b2.z); w.us[7] = f2h(b2.w);
        int byt = ((c & 127) << 4) ^ ((row & 7) << 4);
        *(short8*)(smw + (row << 10) + (byt >> 1)) = w.s;
    }
    // ============ init: logit fc rows [v0, v0+16) -> registers (A-fragments) ============
    const int v0 = iw * 16;
    const int vrowc = (v0 + ml < NV) ? v0 + ml : NV - 1;
    half8 la[8];
    #pragma unroll
    for (int j = 0; j < 8; ++j) {
        const float* src = fcw + (size_t)vrowc * NH + (((wv << 3) + j) << 5) + kl8;
        union { unsigned short us[8]; short8 s; } w;
        #pragma unroll
        for (int e = 0; e < 8; ++e) w.us[e] = f2h(src[e]);
        la[j] = as_h8(w.s);
    }
    // pointwise roles: thread -> (group-local batch b, unit u)
    const int b = tid & 15;
    const int u = tid >> 4;       // 0..15
    float bs[4];
    #pragma unroll
    for (int q = 0; q < 4; ++q)
        bs[q] = Wb[(q << 10) + u0 + u];
    float creg = enc_c[(size_t)(gB + b) * NH + u0 + u];
    // store roles (WAVE 1, tid 64..127): srow = batch, sseg = 4-float segment
    const int srow = (tid & 63) >> 2, sseg = tid & 3;
    float fbs[4];
    #pragma unroll
    for (int r = 0; r < 4; ++r) {
        int v = v0 + (sseg << 2) + r;
        fbs[r] = fcb[v < NV ? v : NV - 1];
    }
    __syncthreads();

    for (int p = 1; p <= TT + 1; ++p) {
        // embedding prefetch (plain cached loads; overlap the spin)
        unsigned short emb[4];
        if (p <= TT) {
            int idx = trg[(gB + b) * TT + p - 1];
            #pragma unroll
            for (int q = 0; q < 4; ++q)
                emb[q] = embT[(size_t)idx * 4096 + (q << 10) + u0 + u];
        }
        // wave 0: fence FIRST (inv hides under the spin), then packed-flag polls
        if (tid < 64) {
            if (FCAD == 1 || (p & (FCAD - 1)) == 1)
                __builtin_amdgcn_fence(__ATOMIC_ACQUIRE, "agent");
            if (p > 1)
                while (__hip_atomic_load(gfl4 + tid, __ATOMIC_RELAXED, AGT) < p - 1) { }
        }
        __syncthreads();   // B1: also drains deferred out stores (wave 1)

        const unsigned short* hh = hbase + (size_t)((p - 1) & (RING - 1)) * 16384;
        // this wave's 8 h fragments (K range wv*256..+255), contiguous blocked reads
        half8 hb[8];
        #pragma unroll
        for (int j = 0; j < 8; ++j) {
            int wgp = (wv << 4) + (j << 1) + (kq >> 1);
            hb[j] = as_h8(*(const short8*)(hh + (wgp << 8) + (ml << 4) + ((kq & 1) << 3)));
        }

        // ---------------- gate phase (critical path) ----------------
        if (p <= TT) {
            f32x4 acc[4] = {};
            #pragma unroll
            for (int j = 0; j < 8; ++j) {
                int kb = (((wv << 3) + j) << 5) + kl8;
                #pragma unroll
                for (int rt = 0; rt < 4; ++rt) {
                    int row = (rt << 4) + ml;
                    int byt = (kb << 1) ^ ((row & 7) << 4);
                    half8 a = as_h8(*(const short8*)(smw + (row << 10) + (byt >> 1)));
                    acc[rt] = __builtin_amdgcn_mfma_f32_16x16x32_f16(a, hb[j], acc[rt], 0, 0, 0);
                }
            }
            #pragma unroll
            for (int rt = 0; rt < 4; ++rt)
                #pragma unroll
                for (int r = 0; r < 4; ++r)
                    gl[wv][rt][rq + r][ml] = acc[rt][r];
            __syncthreads();   // B2
            // pointwise: thread (b, u) sums the 4 K-planes per gate
            float pre[4];
            #pragma unroll
            for (int q = 0; q < 4; ++q)
                pre[q] = gl[0][q][u][b] + gl[1][q][u][b] + gl[2][q][u][b] + gl[3][q][u][b]
                         + bs[q] + bf2f(emb[q]);
            float ii = sigm(pre[0]), ff = sigm(pre[1]);
            float gg = tanh_f(pre[2]), oo = sigm(pre[3]);
            float cc = ff * creg + ii * gg;
            creg = cc;
            ht[b][u] = f2h(oo * tanh_f(cc));
            __syncthreads();   // B3
            // WAVE 0 alone: coalesced publish -> per-wave vmcnt drain -> flag.
            // (vmcnt is per-wave and tid0 is in wave 0 => NO barrier needed;
            //  waves 1-3 fall through to the logit MFMAs during the drain.)
            if (tid < 32) {
                int b2 = tid >> 1, u8 = (tid & 1) << 3;
                unsigned long long lo = *(const unsigned long long*)&ht[b2][u8];
                unsigned long long hi;
                memcpy(&hi, &ht[b2][u8 + 4], 8);
                unsigned short* dst = hbase + (size_t)(p & (RING - 1)) * 16384
                                      + (iw << 8) + (b2 << 4) + u8;
                __hip_atomic_store((unsigned long long*)dst, lo, __ATOMIC_RELAXED, AGT);
                __hip_atomic_store((unsigned long long*)(dst + 4), hi, __ATOMIC_RELAXED, AGT);
                asm volatile("s_waitcnt vmcnt(0)" ::: "memory");  // wave-0 stores acked
                if (tid == 0)
                    __hip_atomic_store(gfl4 + iw, p, __ATOMIC_RELAXED, AGT);  // RELEASE
            }
        }

        // ---------------- logit phase for t = p-2 (uses hb = h_{p-1}) ----------------
        if (p >= 2) {
            f32x4 accl = {};
            #pragma unroll
            for (int j = 0; j < 8; ++j)
                accl = __builtin_amdgcn_mfma_f32_16x16x32_f16(la[j], hb[j], accl, 0, 0, 0);
            #pragma unroll
            for (int r = 0; r < 4; ++r)
                gl[wv][0][rq + r][ml] = accl[r];
            __syncthreads();   // B5
            // fused finalize + full-line stores on WAVE 1 (wave 0 stays store-free)
            if (tid >= 64 && tid < 128) {
                int vq = v0 + (sseg << 2);
                f32x4 val;
                #pragma unroll
                for (int r = 0; r < 4; ++r) {
                    int rowi = (sseg << 2) + r;
                    val[r] = gl[0][0][rowi][srow] + gl[1][0][rowi][srow]
                           + gl[2][0][rowi][srow] + gl[3][0][rowi][srow] + fbs[r];
                }
                float* po = out + ((size_t)(gB + srow) * TT + (p - 2)) * NV + vq;
                if (vq + 3 < NV) {
                    __builtin_nontemporal_store(val, (f32x4*)po);
                } else {
                    #pragma unroll
                    for (int r = 0; r < 4; ++r)
                        if (vq + r < NV) __builtin_nontemporal_store(val[r], po + r);
                }
            }
            // no trailing barrier: next iteration's B1 guards gl reuse
        }
    }
}

extern "C" void kernel_launch(void* const* d_in, const int* in_sizes, int n_in,
                              void* d_out, int out_size, void* d_ws, size_t ws_size,
                              hipStream_t stream) {
    const float* enc_h = (const float*)d_in[0];
    const float* enc_c = (const float*)d_in[1];
    const int* trg = (const int*)d_in[2];
    const float* Ww = (const float*)d_in[3];
    const float* Wb = (const float*)d_in[4];
    const float* fcw = (const float*)d_in[5];
    const float* fcb = (const float*)d_in[6];
    float* out = (float*)d_out;

    unsigned short* embT = (unsigned short*)d_ws;        // 1000 x 4096 bf16 (8 MB)
    unsigned short* hring = embT + (size_t)1000 * 4096;  // [4 grp][RING][16384] fp16

    const size_t embBytes = (size_t)1000 * 4096 * 2;
    const size_t slotBytes = (size_t)16384 * 2;
    const size_t need16 = embBytes + (size_t)NGRP * 16 * slotBytes + 8192;  // ~10.5 MB

    hipLaunchKernelGGL(embT_kernel, dim3(1024), dim3(256), 0, stream, Ww, embT);

    if (ws_size >= need16) {
        int* syn = (int*)(hring + (size_t)NGRP * 16 * 16384);
        hipMemsetAsync(syn, 0, 4096, stream);
        hipLaunchKernelGGL(h0_kernel, dim3(256), dim3(256), 0, stream, enc_h, hring, 16);
        lstm_kernel<16, 8><<<dim3(NGRP * GPW), dim3(256), 0, stream>>>(
            enc_c, trg, Ww, Wb, fcw, fcb, embT, hring, syn, out);
    } else {
        int* syn = (int*)(hring + (size_t)NGRP * 4 * 16384);
        hipMemsetAsync(syn, 0, 4096, stream);
        hipLaunchKernelGGL(h0_kernel, dim3(256), dim3(256), 0, stream, enc_h, hring, 4);
        lstm_kernel<4, 1><<<dim3(NGRP * GPW), dim3(256), 0, stream>>>(
            enc_c, trg, Ww, Wb, fcw, fcb, embT, hring, syn, out);
    }
}